// Round 1
// baseline (903.272 us; speedup 1.0000x reference)
//
#include <hip/hip_runtime.h>

typedef unsigned short u16;
typedef unsigned int u32;
typedef __bf16 bf16x8 __attribute__((ext_vector_type(8)));
typedef _Float16 f16;
typedef _Float16 f16x8 __attribute__((ext_vector_type(8)));
typedef float f32x4 __attribute__((ext_vector_type(4)));

#define B_ 2
#define N_ 65536
#define M_ 16384
#define C1_ 128
#define C2_ 256
#define K1_ 384   // C1+C2
#define O1_ 256   // mlp[1]
#define O2_ 128   // mlp[2]
#define NTI_ 4096     // i-tiles per batch (N_/16)
#define NTJ_ 1024     // j-tiles per batch (M_/16)
#define EPS2_ 6.0e-3f // 2*eps certified bound on |mfma-key - ref-distance| ordering slack

__device__ __forceinline__ u16 f2bf(float f) {
    u32 u = __float_as_uint(f);
    u32 r = (u + 0x7FFFu + ((u >> 16) & 1u)) >> 16;   // RNE
    return (u16)r;
}
__device__ __forceinline__ float bf2f(u16 h) {
    return __uint_as_float(((u32)h) << 16);
}
__device__ __forceinline__ u32 pack2(float lo, float hi) {
    return (u32)f2bf(lo) | ((u32)f2bf(hi) << 16);
}
__device__ __forceinline__ uint4 pack8(float4 a, float4 b) {
    uint4 r;
    r.x = pack2(a.x, a.y); r.y = pack2(a.z, a.w);
    r.z = pack2(b.x, b.y); r.w = pack2(b.z, b.w);
    return r;
}
__device__ __forceinline__ u16 h2u(f16 h) {
    union { f16 h; u16 u; } c; c.h = h; return c.u;
}

// Exact-IEEE fp32 mul with an optimization barrier so the backend can NEVER
// contract it into an FMA (HIP default is -ffp-contract=fast).
__device__ __forceinline__ float mul_rn(float a, float b) {
    float p = __fmul_rn(a, b);
    asm volatile("" : "+v"(p));
    return p;
}
// u2/k2: elementwise-square (each product rounded) + ascending reduce
__device__ __forceinline__ float sq3_np(float x, float y, float z) {
    return __fadd_rn(__fadd_rn(mul_rn(x, x), mul_rn(y, y)), mul_rn(z, z));
}
// Eigen/XLA gebp K=3 dot: ascending k, FMA accumulate into rounded first product
__device__ __forceinline__ float dot3_fma(float a0, float b0, float a1, float b1,
                                          float a2, float b2) {
    return fmaf(a2, b2, fmaf(a1, b1, mul_rn(a0, b0)));
}

// ============================== NN search: MFMA filter + exact refine ======
// key val_ij = k2_j - 2*dot_ij computed by one mfma_f32_16x16x32_f16 per tile:
//   K-slots (A side has -2 folded in; slots 9,10 carry 1.0 so k2 rides in B):
//   A: [-2xh,-2xh,-2xl, -2yh,-2yh,-2yl, -2zh,-2zh,-2zl, 1, 1, 0...]
//   B: [ kxh, kxl, kxh,  kyh, kyl, kyh,  kzh, kzl, kzh, qh, ql, 0...]
// (hi/lo = exact f16 two-term split). |val + u2 - d_ref| <= eps, eps<=3e-3
// worst-case (split<=6.1e-5/coord even with f16-denorm flush, MFMA accum
// <=2e-4, ref rounding <=1e-4). Pass A: rowmin; pass B: candidates with
// val <= rowmin+2eps get the EXACT reference-rounded distance; argmin among
// those with strict-<, ascending-j, smaller-index tiebreak == reference argmin.
// Fragment layout identical to the verified k_gemm1 (A row=lane&15,
// k=(lane>>4)*8+s; C row=(lane>>4)*4+r, col=lane&15). Only lanes<32 hold
// nonzero K, so prep buffers are compact (32 lanes * 16B per tile); lanes>=32
// read a zeroed 16B of workspace (stride 0).

__global__ __launch_bounds__(256) void k_prep_u(const float* __restrict__ unk,
                                                u16* __restrict__ Aprep) {
    int g = blockIdx.x * 256 + threadIdx.x;          // over B*N
    const float* up = unk + (size_t)g * 3;
    float tx = -2.f * up[0], ty = -2.f * up[1], tz = -2.f * up[2];
    f16 xh = (f16)tx; f16 xl = (f16)(tx - (float)xh);
    f16 yh = (f16)ty; f16 yl = (f16)(ty - (float)yh);
    f16 zh = (f16)tz; f16 zl = (f16)(tz - (float)zh);
    u16 s[16];
    s[0] = h2u(xh); s[1] = h2u(xh); s[2] = h2u(xl);
    s[3] = h2u(yh); s[4] = h2u(yh); s[5] = h2u(yl);
    s[6] = h2u(zh); s[7] = h2u(zh); s[8] = h2u(zl);
    s[9] = 0x3C00u; s[10] = 0x3C00u;                 // f16 1.0
    s[11] = s[12] = s[13] = s[14] = s[15] = 0;
    int tt = g >> 4, R = g & 15;
    *(uint4*)(Aprep + ((size_t)tt * 32 + R) * 8) = *(uint4*)&s[0];
    *(uint4*)(Aprep + ((size_t)tt * 32 + 16 + R) * 8) = *(uint4*)&s[8];
}

__global__ __launch_bounds__(256) void k_prep_k(const float* __restrict__ kn,
                                                u16* __restrict__ Bprep,
                                                float4* __restrict__ kco) {
    int g = blockIdx.x * 256 + threadIdx.x;          // over B*M
    const float* kp = kn + (size_t)g * 3;
    float x = kp[0], y = kp[1], z = kp[2];
    float qv = sq3_np(x, y, z);                       // EXACT ref k2 sequence
    f16 xh = (f16)x; f16 xl = (f16)(x - (float)xh);
    f16 yh = (f16)y; f16 yl = (f16)(y - (float)yh);
    f16 zh = (f16)z; f16 zl = (f16)(z - (float)zh);
    f16 qh = (f16)qv; f16 ql = (f16)(qv - (float)qh);
    u16 s[16];
    s[0] = h2u(xh); s[1] = h2u(xl); s[2] = h2u(xh);
    s[3] = h2u(yh); s[4] = h2u(yl); s[5] = h2u(yh);
    s[6] = h2u(zh); s[7] = h2u(zl); s[8] = h2u(zh);
    s[9] = h2u(qh); s[10] = h2u(ql);
    s[11] = s[12] = s[13] = s[14] = s[15] = 0;
    int tt = g >> 4, R = g & 15;
    *(uint4*)(Bprep + ((size_t)tt * 32 + R) * 8) = *(uint4*)&s[0];
    *(uint4*)(Bprep + ((size_t)tt * 32 + 16 + R) * 8) = *(uint4*)&s[8];
    kco[g] = make_float4(x, y, z, qv);
}

#define NRT_ 4   // row-tiles per wave (64 rows/wave, 256 rows/block)

// Pass A: thr[row] = min_j val + 2eps
__global__ __launch_bounds__(256, 2) void k_nn_min(const u16* __restrict__ Aprep,
                                                   const u16* __restrict__ Bprep,
                                                   const u16* __restrict__ zpage,
                                                   float* __restrict__ thr) {
    const int t = threadIdx.x, b = blockIdx.y;
    const int lane = t & 63, w = t >> 6;
    const int q = lane >> 4, R = lane & 15;
    const int rowblk = blockIdx.x * 256 + w * 64;
    const int tA = b * NTI_ + (rowblk >> 4);
    f16x8 af[NRT_];
#pragma unroll
    for (int rt = 0; rt < NRT_; ++rt) {
        const u16* ap = (lane < 32) ? (Aprep + ((size_t)(tA + rt) * 32 + lane) * 8) : zpage;
        af[rt] = *(const f16x8*)ap;
    }
    const u16* bptr = (lane < 32) ? (Bprep + ((size_t)b * NTJ_ * 32 + lane) * 8) : zpage;
    const size_t bstep = (lane < 32) ? 256 : 0;       // u16 units per tile
    float rm[NRT_][4];
#pragma unroll
    for (int rt = 0; rt < NRT_; ++rt)
#pragma unroll
        for (int r2 = 0; r2 < 4; ++r2) rm[rt][r2] = 3.4e38f;

#pragma unroll 2
    for (int tj = 0; tj < NTJ_; ++tj) {
        f16x8 bf = *(const f16x8*)bptr;
        bptr += bstep;
        f32x4 acc[NRT_];
#pragma unroll
        for (int rt = 0; rt < NRT_; ++rt)
            acc[rt] = __builtin_amdgcn_mfma_f32_16x16x32_f16(
                af[rt], bf, (f32x4){0.f, 0.f, 0.f, 0.f}, 0, 0, 0);
#pragma unroll
        for (int rt = 0; rt < NRT_; ++rt)
#pragma unroll
            for (int r2 = 0; r2 < 4; ++r2)
                rm[rt][r2] = fminf(rm[rt][r2], acc[rt][r2]);
    }
#pragma unroll
    for (int rt = 0; rt < NRT_; ++rt)
#pragma unroll
        for (int r2 = 0; r2 < 4; ++r2) {
            float v = rm[rt][r2];
            v = fminf(v, __shfl_xor(v, 1));
            v = fminf(v, __shfl_xor(v, 2));
            v = fminf(v, __shfl_xor(v, 4));
            v = fminf(v, __shfl_xor(v, 8));
            rm[rt][r2] = v;
        }
    if (R == 0) {
#pragma unroll
        for (int rt = 0; rt < NRT_; ++rt)
#pragma unroll
            for (int r2 = 0; r2 < 4; ++r2)
                thr[b * N_ + rowblk + rt * 16 + q * 4 + r2] = rm[rt][r2] + EPS2_;
    }
}

// Pass B: exact reference-rounded argmin among candidates val <= thr
__global__ __launch_bounds__(256, 2) void k_nn_arg(const u16* __restrict__ Aprep,
                                                   const u16* __restrict__ Bprep,
                                                   const u16* __restrict__ zpage,
                                                   const float* __restrict__ thr,
                                                   const float* __restrict__ unk,
                                                   const float4* __restrict__ kco,
                                                   int* __restrict__ idx) {
    const int t = threadIdx.x, b = blockIdx.y;
    const int lane = t & 63, w = t >> 6;
    const int q = lane >> 4, R = lane & 15;
    const int rowblk = blockIdx.x * 256 + w * 64;
    const int tA = b * NTI_ + (rowblk >> 4);
    f16x8 af[NRT_];
#pragma unroll
    for (int rt = 0; rt < NRT_; ++rt) {
        const u16* ap = (lane < 32) ? (Aprep + ((size_t)(tA + rt) * 32 + lane) * 8) : zpage;
        af[rt] = *(const f16x8*)ap;
    }
    const u16* bptr = (lane < 32) ? (Bprep + ((size_t)b * NTJ_ * 32 + lane) * 8) : zpage;
    const size_t bstep = (lane < 32) ? 256 : 0;
    const float4* kcb = kco + (size_t)b * M_;
    const float* ub = unk + (size_t)b * N_ * 3;
    float th[NRT_][4], bd[NRT_][4];
    int bi[NRT_][4];
#pragma unroll
    for (int rt = 0; rt < NRT_; ++rt)
#pragma unroll
        for (int r2 = 0; r2 < 4; ++r2) {
            th[rt][r2] = thr[b * N_ + rowblk + rt * 16 + q * 4 + r2];
            bd[rt][r2] = 3.4e38f;
            bi[rt][r2] = 0x7fffffff;
        }

    for (int tj = 0; tj < NTJ_; ++tj) {
        f16x8 bf = *(const f16x8*)bptr;
        bptr += bstep;
        f32x4 acc[NRT_];
#pragma unroll
        for (int rt = 0; rt < NRT_; ++rt)
            acc[rt] = __builtin_amdgcn_mfma_f32_16x16x32_f16(
                af[rt], bf, (f32x4){0.f, 0.f, 0.f, 0.f}, 0, 0, 0);
#pragma unroll
        for (int rt = 0; rt < NRT_; ++rt) {
            f32x4 a = acc[rt];
            unsigned long long m = __ballot(a[0] <= th[rt][0]) | __ballot(a[1] <= th[rt][1])
                                 | __ballot(a[2] <= th[rt][2]) | __ballot(a[3] <= th[rt][3]);
            if (m) {                                     // rare (~5% of tiles)
                int j = tj * 16 + R;
                float4 kc = kcb[j];
#pragma unroll
                for (int r2 = 0; r2 < 4; ++r2) {
                    if (a[r2] <= th[rt][r2]) {
                        int row = rowblk + rt * 16 + q * 4 + r2;
                        const float* up = ub + (size_t)row * 3;
                        float x = up[0], y = up[1], z = up[2];
                        float uq = sq3_np(x, y, z);
                        float dot = dot3_fma(x, kc.x, y, kc.y, z, kc.z);
                        float d = __fadd_rn(fmaf(-2.0f, dot, uq), kc.w);
                        bool lt = d < bd[rt][r2];        // strict <, ascending j
                        bd[rt][r2] = lt ? d : bd[rt][r2];
                        bi[rt][r2] = lt ? j : bi[rt][r2];
                    }
                }
            }
        }
    }
    // cross-lane argmin over the 16 col-classes; tie -> smaller j (first-wins)
#pragma unroll
    for (int rt = 0; rt < NRT_; ++rt)
#pragma unroll
        for (int r2 = 0; r2 < 4; ++r2) {
            float d = bd[rt][r2];
            int ii = bi[rt][r2];
#pragma unroll
            for (int mm = 1; mm <= 8; mm <<= 1) {
                float od = __shfl_xor(d, mm);
                int oi = __shfl_xor(ii, mm);
                bool take = (od < d) || (od == d && oi < ii);
                d = take ? od : d;
                ii = take ? oi : ii;
            }
            if (R == 0) idx[b * N_ + rowblk + rt * 16 + q * 4 + r2] = ii;
        }
}

// ------------------------------------------- transpose known_feats -> (b,m,c) bf16
__global__ __launch_bounds__(256) void k_tr_kf(const float* __restrict__ kf,
                                               u16* __restrict__ kfT) {
    __shared__ float lt[64][65];
    const int t = threadIdx.x, b = blockIdx.z;
    const int j0 = blockIdx.x * 64, c0 = blockIdx.y * 64;
    const int jl = t & 63, cl4 = t >> 6;
#pragma unroll
    for (int p = 0; p < 16; ++p) {
        int c = c0 + cl4 + p * 4;
        lt[cl4 + p * 4][jl] = kf[((size_t)(b * C2_ + c)) * M_ + j0 + jl];
    }
    __syncthreads();
    const int cl = t & 63, jr4 = t >> 6;
#pragma unroll
    for (int p = 0; p < 16; ++p) {
        int j = j0 + jr4 + p * 4;
        kfT[((size_t)(b * M_ + j)) * C2_ + c0 + cl] = f2bf(lt[cl][jr4 + p * 4]);
    }
}

// ------------------------------- transpose unknow_feats into newF[...,256:384) bf16
__global__ __launch_bounds__(256) void k_tr_uf(const float* __restrict__ uf,
                                               u16* __restrict__ newF) {
    __shared__ float lt[64][65];
    const int t = threadIdx.x, b = blockIdx.z;
    const int i0 = blockIdx.x * 64, c0 = blockIdx.y * 64;
    const int il = t & 63, cl4 = t >> 6;
#pragma unroll
    for (int p = 0; p < 16; ++p) {
        int c = c0 + cl4 + p * 4;
        lt[cl4 + p * 4][il] = uf[((size_t)(b * C1_ + c)) * N_ + i0 + il];
    }
    __syncthreads();
    const int cl = t & 63, ir4 = t >> 6;
#pragma unroll
    for (int p = 0; p < 16; ++p) {
        int i = i0 + ir4 + p * 4;
        newF[((size_t)(b * N_ + i)) * K1_ + C2_ + c0 + cl] = f2bf(lt[cl][ir4 + p * 4]);
    }
}

// ------------------------------------ gather kfT rows into newF[...,0:256) (dense)
__global__ __launch_bounds__(256) void k_gather(const u16* __restrict__ kfT,
                                                const int* __restrict__ idx,
                                                u16* __restrict__ newF) {
    const int t = threadIdx.x, b = blockIdx.y;
    const int il = t >> 5, qq = t & 31;
    const int i = blockIdx.x * 8 + il;
    const int j = idx[b * N_ + i];
    const uint4* src = (const uint4*)(kfT + ((size_t)(b * M_ + j)) * C2_) + qq;
    uint4* dst = (uint4*)(newF + ((size_t)(b * N_ + i)) * K1_) + qq;
    *dst = *src;
}

// ---------------------------------------------------------------- GEMM1
// y1[b][i][o] (bf16) = newF[b][i][:] . w1[o][:]   tiles 128x128, BK=32
__global__ __launch_bounds__(256) void k_gemm1(const u16* __restrict__ newF,
                                               const float* __restrict__ w1,
                                               u16* __restrict__ y1) {
    __shared__ u16 As[128 * 40];
    __shared__ u16 Bs[128 * 40];
    const int t = threadIdx.x, b = blockIdx.z;
    const int i0 = blockIdx.x * 128, o0 = blockIdx.y * 128;
    const int lane = t & 63, wv = t >> 6, wr = wv >> 1, wc = wv & 1;
    const int col = lane & 15, q = lane >> 4;

    const int rA0 = t >> 2, sA0 = t & 3;   // +256 => row+64, same sub
    const u16* aS0 = newF + ((size_t)(b * N_ + i0 + rA0)) * K1_ + sA0 * 8;
    const u16* aS1 = aS0 + (size_t)64 * K1_;
    const float* bS0 = w1 + (size_t)(o0 + rA0) * K1_ + sA0 * 8;
    const float* bS1 = bS0 + (size_t)64 * K1_;
    u16* aD0 = &As[rA0 * 40 + sA0 * 8];
    u16* aD1 = aD0 + 64 * 40;
    u16* bD0 = &Bs[rA0 * 40 + sA0 * 8];
    u16* bD1 = bD0 + 64 * 40;

    f32x4 acc[4][4];
#pragma unroll
    for (int m = 0; m < 4; ++m)
#pragma unroll
        for (int n = 0; n < 4; ++n) acc[m][n] = (f32x4){0.f, 0.f, 0.f, 0.f};

    uint4 a0 = *(const uint4*)aS0, a1 = *(const uint4*)aS1;
    float4 f00 = *(const float4*)bS0, f01 = *(const float4*)(bS0 + 4);
    float4 f10 = *(const float4*)bS1, f11 = *(const float4*)(bS1 + 4);

    for (int ks = 0; ks < 12; ++ks) {
        __syncthreads();
        *(uint4*)aD0 = a0; *(uint4*)aD1 = a1;
        *(uint4*)bD0 = pack8(f00, f01); *(uint4*)bD1 = pack8(f10, f11);
        __syncthreads();
        if (ks < 11) {
            int ko = (ks + 1) * 32;
            a0 = *(const uint4*)(aS0 + ko); a1 = *(const uint4*)(aS1 + ko);
            f00 = *(const float4*)(bS0 + ko); f01 = *(const float4*)(bS0 + ko + 4);
            f10 = *(const float4*)(bS1 + ko); f11 = *(const float4*)(bS1 + ko + 4);
        }
        const u16* ap = &As[(wr * 64 + col) * 40 + q * 8];
        const u16* bp = &Bs[(wc * 64 + col) * 40 + q * 8];
        bf16x8 af[4], bfr[4];
#pragma unroll
        for (int m = 0; m < 4; ++m) af[m] = *(const bf16x8*)(ap + m * 640);
#pragma unroll
        for (int n = 0; n < 4; ++n) bfr[n] = *(const bf16x8*)(bp + n * 640);
#pragma unroll
        for (int m = 0; m < 4; ++m)
#pragma unroll
            for (int n = 0; n < 4; ++n)
                acc[m][n] = __builtin_amdgcn_mfma_f32_16x16x32_bf16(af[m], bfr[n], acc[m][n], 0, 0, 0);
    }
#pragma unroll
    for (int m = 0; m < 4; ++m)
#pragma unroll
        for (int n = 0; n < 4; ++n) {
            int go = o0 + wc * 64 + n * 16 + col;
#pragma unroll
            for (int r = 0; r < 4; ++r) {
                int gi = i0 + wr * 64 + m * 16 + q * 4 + r;
                y1[((size_t)(b * N_ + gi)) * O1_ + go] = f2bf(acc[m][n][r]);
            }
        }
}

// ------------------------------------------------- BN stats over y1 (bf16, 256 ch)
__global__ __launch_bounds__(256) void k_stats_bf16(const u16* __restrict__ y1,
                                                    float* __restrict__ sum,
                                                    float* __restrict__ sq) {
    const int t = threadIdx.x;
    const int row0 = blockIdx.x * 1024;
    float s = 0.f, qq = 0.f;
    for (int r = 0; r < 1024; ++r) {
        float v = bf2f(y1[((size_t)(row0 + r)) * O1_ + t]);
        s += v; qq = fmaf(v, v, qq);
    }
    atomicAdd(&sum[t], s);
    atomicAdd(&sq[t], qq);
}

// ------------------------------------------------- BN stats over y2 (f32, 128 ch)
__global__ __launch_bounds__(256) void k_stats_f32(const float* __restrict__ y2,
                                                   float* __restrict__ sum,
                                                   float* __restrict__ sq) {
    const int t = threadIdx.x;
    const int o = t & 127, h = t >> 7;
    const int row0 = blockIdx.x * 1024;
    float s = 0.f, qq = 0.f;
    for (int r = 0; r < 512; ++r) {
        float v = y2[((size_t)(row0 + r * 2 + h)) * O2_ + o];
        s += v; qq = fmaf(v, v, qq);
    }
    atomicAdd(&sum[o], s);
    atomicAdd(&sq[o], qq);
}

__global__ void k_bn_fin(const float* __restrict__ sum, const float* __restrict__ sq,
                         const float* __restrict__ gamma, const float* __restrict__ beta,
                         float* __restrict__ scale, float* __restrict__ bias,
                         int C, float invN) {
    int t = threadIdx.x;
    if (t < C) {
        float mean = sum[t] * invN;
        float var = sq[t] * invN - mean * mean;
        float rs = rsqrtf(var + 1e-5f);
        float sc = gamma[t] * rs;
        scale[t] = sc;
        bias[t] = beta[t] - mean * sc;
    }
}

// ---------------------------------------------------------------- GEMM2
// y2[b][i][o] (f32) = relu(bn1(y1))[b][i][:] . w2[o][:]  (BN1 fused in A-staging)
__global__ __launch_bounds__(256) void k_gemm2(const u16* __restrict__ y1,
                                               const float* __restrict__ w2,
                                               const float* __restrict__ s1,
                                               const float* __restrict__ b1,
                                               float* __restrict__ y2) {
    __shared__ u16 As[128 * 40];
    __shared__ u16 Bs[128 * 40];
    const int t = threadIdx.x, b = blockIdx.z;
    const int i0 = blockIdx.x * 128;
    const int lane = t & 63, wv = t >> 6, wr = wv >> 1, wc = wv & 1;
    const int col = lane & 15, q = lane >> 4;

    const int rA0 = t >> 2, sA0 = t & 3;
    const u16* aS0 = y1 + ((size_t)(b * N_ + i0 + rA0)) * O1_ + sA0 * 8;
    const u16* aS1 = aS0 + (size_t)64 * O1_;
    const float* bS0 = w2 + (size_t)rA0 * O1_ + sA0 * 8;
    const float* bS1 = bS0 + (size_t)64 * O1_;
    u16* aD0 = &As[rA0 * 40 + sA0 * 8];
    u16* aD1 = aD0 + 64 * 40;
    u16* bD0 = &Bs[rA0 * 40 + sA0 * 8];
    u16* bD1 = bD0 + 64 * 40;

    f32x4 acc[4][4];
#pragma unroll
    for (int m = 0; m < 4; ++m)
#pragma unroll
        for (int n = 0; n < 4; ++n) acc[m][n] = (f32x4){0.f, 0.f, 0.f, 0.f};

    uint4 a0 = *(const uint4*)aS0, a1 = *(const uint4*)aS1;
    float4 f00 = *(const float4*)bS0, f01 = *(const float4*)(bS0 + 4);
    float4 f10 = *(const float4*)bS1, f11 = *(const float4*)(bS1 + 4);

    for (int ks = 0; ks < 8; ++ks) {
        int oc = ks * 32 + sA0 * 8;
        float4 sc0 = *(const float4*)(s1 + oc), sc1 = *(const float4*)(s1 + oc + 4);
        float4 bb0 = *(const float4*)(b1 + oc), bb1 = *(const float4*)(b1 + oc + 4);
        uint4 h0, h1;
        {
            const u16* hs = (const u16*)&a0;
            float v[8];
            v[0] = fmaxf(fmaf(bf2f(hs[0]), sc0.x, bb0.x), 0.f);
            v[1] = fmaxf(fmaf(bf2f(hs[1]), sc0.y, bb0.y), 0.f);
            v[2] = fmaxf(fmaf(bf2f(hs[2]), sc0.z, bb0.z), 0.f);
            v[3] = fmaxf(fmaf(bf2f(hs[3]), sc0.w, bb0.w), 0.f);
            v[4] = fmaxf(fmaf(bf2f(hs[4]), sc1.x, bb1.x), 0.f);
            v[5] = fmaxf(fmaf(bf2f(hs[5]), sc1.y, bb1.y), 0.f);
            v[6] = fmaxf(fmaf(bf2f(hs[6]), sc1.z, bb1.z), 0.f);
            v[7] = fmaxf(fmaf(bf2f(hs[7]), sc1.w, bb1.w), 0.f);
            h0.x = pack2(v[0], v[1]); h0.y = pack2(v[2], v[3]);
            h0.z = pack2(v[4], v[5]); h0.w = pack2(v[6], v[7]);
        }
        {
            const u16* hs = (const u16*)&a1;
            float v[8];
            v[0] = fmaxf(fmaf(bf2f(hs[0]), sc0.x, bb0.x), 0.f);
            v[1] = fmaxf(fmaf(bf2f(hs[1]), sc0.y, bb0.y), 0.f);
            v[2] = fmaxf(fmaf(bf2f(hs[2]), sc0.z, bb0.z), 0.f);
            v[3] = fmaxf(fmaf(bf2f(hs[3]), sc0.w, bb0.w), 0.f);
            v[4] = fmaxf(fmaf(bf2f(hs[4]), sc1.x, bb1.x), 0.f);
            v[5] = fmaxf(fmaf(bf2f(hs[5]), sc1.y, bb1.y), 0.f);
            v[6] = fmaxf(fmaf(bf2f(hs[6]), sc1.z, bb1.z), 0.f);
            v[7] = fmaxf(fmaf(bf2f(hs[7]), sc1.w, bb1.w), 0.f);
            h1.x = pack2(v[0], v[1]); h1.y = pack2(v[2], v[3]);
            h1.z = pack2(v[4], v[5]); h1.w = pack2(v[6], v[7]);
        }
        __syncthreads();
        *(uint4*)aD0 = h0; *(uint4*)aD1 = h1;
        *(uint4*)bD0 = pack8(f00, f01); *(uint4*)bD1 = pack8(f10, f11);
        __syncthreads();
        if (ks < 7) {
            int ko = (ks + 1) * 32;
            a0 = *(const uint4*)(aS0 + ko); a1 = *(const uint4*)(aS1 + ko);
            f00 = *(const float4*)(bS0 + ko); f01 = *(const float4*)(bS0 + ko + 4);
            f10 = *(const float4*)(bS1 + ko); f11 = *(const float4*)(bS1 + ko + 4);
        }
        const u16* ap = &As[(wr * 64 + col) * 40 + q * 8];
        const u16* bp = &Bs[(wc * 64 + col) * 40 + q * 8];
        bf16x8 af[4], bfr[4];
#pragma unroll
        for (int m = 0; m < 4; ++m) af[m] = *(const bf16x8*)(ap + m * 640);
#pragma unroll
        for (int n = 0; n < 4; ++n) bfr[n] = *(const bf16x8*)(bp + n * 640);
#pragma unroll
        for (int m = 0; m < 4; ++m)
#pragma unroll
            for (int n = 0; n < 4; ++n)
                acc[m][n] = __builtin_amdgcn_mfma_f32_16x16x32_bf16(af[m], bfr[n], acc[m][n], 0, 0, 0);
    }
#pragma unroll
    for (int m = 0; m < 4; ++m)
#pragma unroll
        for (int n = 0; n < 4; ++n) {
            int go = wc * 64 + n * 16 + col;
#pragma unroll
            for (int r = 0; r < 4; ++r) {
                int gi = i0 + wr * 64 + m * 16 + q * 4 + r;
                y2[((size_t)(b * N_ + gi)) * O2_ + go] = acc[m][n][r];
            }
        }
}

// ---------------------------- BN2 affine + ReLU + transpose (b,i,o)->(b,o,i) out
__global__ __launch_bounds__(256) void k_out(const float* __restrict__ y2,
                                             const float* __restrict__ s2,
                                             const float* __restrict__ b2,
                                             float* __restrict__ out) {
    __shared__ float lt[64 * 65];
    const int t = threadIdx.x, b = blockIdx.z;
    const int i0 = blockIdx.x * 64, o0 = blockIdx.y * 64;
    const int oc = t & 63, ir4 = t >> 6;
    const float sc = s2[o0 + oc], bs = b2[o0 + oc];
#pragma unroll
    for (int p = 0; p < 16; ++p) {
        int i = i0 + ir4 + p * 4;
        float v = y2[((size_t)(b * N_ + i)) * O2_ + o0 + oc];
        lt[oc * 65 + ir4 + p * 4] = fmaxf(fmaf(v, sc, bs), 0.f);
    }
    __syncthreads();
    const int il = t & 63, or4 = t >> 6;
#pragma unroll
    for (int p = 0; p < 16; ++p) {
        int o = o0 + or4 + p * 4;
        out[((size_t)(b * O2_ + o)) * N_ + i0 + il] = lt[(or4 + p * 4) * 65 + il];
    }
}

extern "C" void kernel_launch(void* const* d_in, const int* in_sizes, int n_in,
                              void* d_out, int out_size, void* d_ws, size_t ws_size,
                              hipStream_t stream) {
    const float* unknown = (const float*)d_in[0];
    const float* known   = (const float*)d_in[1];
    const float* uf      = (const float*)d_in[2];
    const float* kf      = (const float*)d_in[3];
    const float* w1      = (const float*)d_in[4];
    const float* g1      = (const float*)d_in[5];
    const float* be1     = (const float*)d_in[6];
    const float* w2      = (const float*)d_in[7];
    const float* g2      = (const float*)d_in[8];
    const float* be2     = (const float*)d_in[9];
    float* out = (float*)d_out;

    char* w = (char*)d_ws;
    // stats block (zeroed each call): bn1_sum[256] bn1_sq[256] bn2_sum[128] bn2_sq[128]
    // NOTE: this zeroed region doubles as the NN kernels' zero-page (lanes>=32
    // read 16B of zeros from it; k_stats_* only write to it AFTER the NN phase).
    float* bn1_sum = (float*)w;
    float* bn1_sq  = bn1_sum + 256;
    float* bn2_sum = bn1_sq + 256;
    float* bn2_sq  = bn2_sum + 128;
    float* s1 = (float*)(w + 4096);     // 256
    float* b1 = s1 + 256;               // 256
    float* s2 = b1 + 256;               // 128
    float* b2 = s2 + 128;               // 128
    int* idx = (int*)(w + 8192);                        // 512 KiB
    u16* newF = (u16*)(w + 532480);                     // (B,n,384) bf16 = 100.7 MB
    float* y2 = (float*)(w + 532480);                   // alias (newF dead by GEMM2)
    size_t R2 = 532480 + 100663296ULL;
    // NN scratch (dead before y1 is written):
    u16*   Aprep = (u16*)(w + R2);                      // 4 MiB (8192 tiles * 512B)
    u16*   Bprep = (u16*)(w + R2 + 4194304ULL);         // 1 MiB (2048 tiles * 512B)
    float4* kco  = (float4*)(w + R2 + 5242880ULL);      // 512 KiB
    float* thr   = (float*)(w + R2 + 5767168ULL);       // 512 KiB
    u16*  kfT = (u16*)(w + R2 + 16777216ULL);           // 16.7MB (dead before y1)
    u16*   y1 = (u16*)(w + R2);                         // (B,n,256) bf16 = 67 MB

    hipMemsetAsync(w, 0, 3072, stream);   // zero BN accumulators (+ NN zero-page)

    k_prep_u<<<512, 256, 0, stream>>>(unknown, Aprep);
    k_prep_k<<<128, 256, 0, stream>>>(known, Bprep, kco);
    k_nn_min<<<dim3(256, B_), 256, 0, stream>>>(Aprep, Bprep, (const u16*)w, thr);
    k_nn_arg<<<dim3(256, B_), 256, 0, stream>>>(Aprep, Bprep, (const u16*)w, thr,
                                                unknown, kco, idx);
    k_tr_kf<<<dim3(256, 4, 2), 256, 0, stream>>>(kf, kfT);
    k_tr_uf<<<dim3(1024, 2, 2), 256, 0, stream>>>(uf, newF);
    k_gather<<<dim3(8192, 2), 256, 0, stream>>>(kfT, idx, newF);
    k_gemm1<<<dim3(512, 2, 2), 256, 0, stream>>>(newF, w1, y1);
    k_stats_bf16<<<128, 256, 0, stream>>>(y1, bn1_sum, bn1_sq);
    k_bn_fin<<<1, 256, 0, stream>>>(bn1_sum, bn1_sq, g1, be1, s1, b1, 256, 1.f / 131072.f);
    k_gemm2<<<dim3(512, 1, 2), 256, 0, stream>>>(y1, w2, s1, b1, y2);
    k_stats_f32<<<128, 256, 0, stream>>>(y2, bn2_sum, bn2_sq);
    k_bn_fin<<<1, 256, 0, stream>>>(bn2_sum, bn2_sq, g2, be2, s2, b2, 128, 1.f / 131072.f);
    k_out<<<dim3(1024, 2, 2), 256, 0, stream>>>(y2, s2, b2, out);
}

// Round 2
// 717.097 us; speedup vs baseline: 1.2596x; 1.2596x over previous
//
#include <hip/hip_runtime.h>

typedef unsigned short u16;
typedef unsigned int u32;
typedef __bf16 bf16x8 __attribute__((ext_vector_type(8)));
typedef _Float16 f16;
typedef _Float16 f16x8 __attribute__((ext_vector_type(8)));
typedef float f32x4 __attribute__((ext_vector_type(4)));
typedef float f32x16 __attribute__((ext_vector_type(16)));

#define B_ 2
#define N_ 65536
#define M_ 16384
#define C1_ 128
#define C2_ 256
#define K1_ 384   // C1+C2
#define O1_ 256   // mlp[1]
#define O2_ 128   // mlp[2]
#define JT_ 512       // 32-wide j-tiles per batch (M_/32)
#define CH_ 32        // j-tiles per LDS chunk (32 KB)
#define NCH_ (JT_/CH_)
#define EPS2_ 6.0e-3f // 2*eps certified ordering slack (same arithmetic as verified round-1 filter)

__device__ __forceinline__ u16 f2bf(float f) {
    u32 u = __float_as_uint(f);
    u32 r = (u + 0x7FFFu + ((u >> 16) & 1u)) >> 16;   // RNE
    return (u16)r;
}
__device__ __forceinline__ float bf2f(u16 h) {
    return __uint_as_float(((u32)h) << 16);
}
__device__ __forceinline__ u32 pack2(float lo, float hi) {
    return (u32)f2bf(lo) | ((u32)f2bf(hi) << 16);
}
__device__ __forceinline__ uint4 pack8(float4 a, float4 b) {
    uint4 r;
    r.x = pack2(a.x, a.y); r.y = pack2(a.z, a.w);
    r.z = pack2(b.x, b.y); r.w = pack2(b.z, b.w);
    return r;
}
__device__ __forceinline__ u16 h2u(f16 h) {
    union { f16 h; u16 u; } c; c.h = h; return c.u;
}

// Exact-IEEE fp32 mul with an optimization barrier so the backend can NEVER
// contract it into an FMA (HIP default is -ffp-contract=fast).
__device__ __forceinline__ float mul_rn(float a, float b) {
    float p = __fmul_rn(a, b);
    asm volatile("" : "+v"(p));
    return p;
}
// u2/k2: elementwise-square (each product rounded) + ascending reduce
__device__ __forceinline__ float sq3_np(float x, float y, float z) {
    return __fadd_rn(__fadd_rn(mul_rn(x, x), mul_rn(y, y)), mul_rn(z, z));
}
// Eigen/XLA gebp K=3 dot: ascending k, FMA accumulate into rounded first product
__device__ __forceinline__ float dot3_fma(float a0, float b0, float a1, float b1,
                                          float a2, float b2) {
    return fmaf(a2, b2, fmaf(a1, b1, mul_rn(a0, b0)));
}

// ============================== NN search: 32x32x16 MFMA filter + exact refine
// key val_ij = k2_j - 2*dot_ij via one mfma_f32_32x32x16_f16 per 32x32 tile.
// K-slot layout (A lane l holds row l&31, k=(l>>5)*8+e; B lane l holds col l&31,
// same k pattern; C/D: col=lane&31, row=(reg&3)+8*(reg>>2)+4*(lane>>5)):
//   k 0..7  : A=[Xh,Xh,Xl, Yh,Yh,Yl, Zh,Zh]   B=[kxh,kxl,kxh, kyh,kyl,kyh, kzh,kzl]
//   k 8..15 : A=[Zl, 1, 1, 0...]              B=[kzh, qh, ql, 0...]
// with X=-2x etc (hi/lo exact f16 split), q = exact-ref k2. Identical product
// terms to the verified round-1 filter => same eps bound; EPS2_ unchanged.
// Pass A (in-kernel): rowmin -> th (registers). Pass B: re-stream B, flag
// val<=th, exact reference-rounded d for flagged pairs, LDS atomicMin on
// packed (monotonic(d)<<32 | j)  == lexicographic (d, j) min == strict-<,
// ascending-j first-wins reference argmin.

__global__ __launch_bounds__(256) void k_prep_u(const float* __restrict__ unk,
                                                u16* __restrict__ Aprep) {
    int g = blockIdx.x * 256 + threadIdx.x;          // over B*N
    const float* up = unk + (size_t)g * 3;
    float tx = -2.f * up[0], ty = -2.f * up[1], tz = -2.f * up[2];
    f16 xh = (f16)tx; f16 xl = (f16)(tx - (float)xh);
    f16 yh = (f16)ty; f16 yl = (f16)(ty - (float)yh);
    f16 zh = (f16)tz; f16 zl = (f16)(tz - (float)zh);
    u16 lo[8] = {h2u(xh), h2u(xh), h2u(xl), h2u(yh), h2u(yh), h2u(yl), h2u(zh), h2u(zh)};
    u16 hi[8] = {h2u(zl), 0x3C00u, 0x3C00u, 0, 0, 0, 0, 0};
    u16* tb = Aprep + ((size_t)(g >> 5)) * 512;      // tile = 64 lanes * 8 u16
    int r = g & 31;
    *(uint4*)(tb + r * 8) = *(uint4*)lo;
    *(uint4*)(tb + (r + 32) * 8) = *(uint4*)hi;
}

__global__ __launch_bounds__(256) void k_prep_k(const float* __restrict__ kn,
                                                u16* __restrict__ Bprep,
                                                float4* __restrict__ kco) {
    int g = blockIdx.x * 256 + threadIdx.x;          // over B*M
    const float* kp = kn + (size_t)g * 3;
    float x = kp[0], y = kp[1], z = kp[2];
    float qv = sq3_np(x, y, z);                       // EXACT ref k2 sequence
    f16 xh = (f16)x; f16 xl = (f16)(x - (float)xh);
    f16 yh = (f16)y; f16 yl = (f16)(y - (float)yh);
    f16 zh = (f16)z; f16 zl = (f16)(z - (float)zh);
    f16 qh = (f16)qv; f16 ql = (f16)(qv - (float)qh);
    u16 lo[8] = {h2u(xh), h2u(xl), h2u(xh), h2u(yh), h2u(yl), h2u(yh), h2u(zh), h2u(zl)};
    u16 hi[8] = {h2u(zh), h2u(qh), h2u(ql), 0, 0, 0, 0, 0};
    u16* tb = Bprep + ((size_t)(g >> 5)) * 512;
    int r = g & 31;
    *(uint4*)(tb + r * 8) = *(uint4*)lo;
    *(uint4*)(tb + (r + 32) * 8) = *(uint4*)hi;
    kco[g] = make_float4(x, y, z, qv);
}

__global__ __launch_bounds__(256, 2) void k_nn(
        const u16* __restrict__ Aprep, const u16* __restrict__ Bprep,
        const float* __restrict__ unk, const float4* __restrict__ kco,
        int* __restrict__ idx) {
    __shared__ u16 sB[2][CH_ * 512];                 // 2 x 32 KB
    __shared__ unsigned long long cand[256];
    const int t = threadIdx.x, b = blockIdx.y;
    const int lane = t & 63, w = t >> 6;
    const int rowbase = blockIdx.x * 256;            // 256 rows per block
    // A fragments: wave w owns rows [w*64, w*64+64) = 2 row-tiles of 32
    const u16* at = Aprep + (((size_t)(b * N_ + rowbase + w * 64)) >> 5) * 512;
    const f16x8 af0 = *(const f16x8*)(at + lane * 8);
    const f16x8 af1 = *(const f16x8*)(at + 512 + lane * 8);
    const u16* Bsrc = Bprep + (size_t)b * (JT_ * 512);
    cand[t] = ~0ULL;

    uint4 vs0, vs1, vs2, vs3, vs4, vs5, vs6, vs7;
#define STAGEV(c) { const u16* sp = Bsrc + (size_t)(c) * (CH_ * 512) + t * 8;      \
    vs0 = *(const uint4*)sp;            vs1 = *(const uint4*)(sp + 2048);          \
    vs2 = *(const uint4*)(sp + 4096);   vs3 = *(const uint4*)(sp + 6144);          \
    vs4 = *(const uint4*)(sp + 8192);   vs5 = *(const uint4*)(sp + 10240);         \
    vs6 = *(const uint4*)(sp + 12288);  vs7 = *(const uint4*)(sp + 14336); }
#define WRITEV(bi) { u16* dp = &sB[bi][t * 8];                                     \
    *(uint4*)dp = vs0;             *(uint4*)(dp + 2048) = vs1;                     \
    *(uint4*)(dp + 4096) = vs2;    *(uint4*)(dp + 6144) = vs3;                     \
    *(uint4*)(dp + 8192) = vs4;    *(uint4*)(dp + 10240) = vs5;                    \
    *(uint4*)(dp + 12288) = vs6;   *(uint4*)(dp + 14336) = vs7; }

    // ---------------- pass A: rowmin ----------------
    f32x16 rm0, rm1;
#pragma unroll
    for (int r = 0; r < 16; ++r) { rm0[r] = 3.4e38f; rm1[r] = 3.4e38f; }

    STAGEV(0); WRITEV(0);
    __syncthreads();
    for (int c = 0; c < NCH_; ++c) {
        if (c + 1 < NCH_) STAGEV(c + 1);
        const u16* bb = sB[c & 1];
#pragma unroll 4
        for (int tt = 0; tt < CH_; ++tt) {
            f16x8 bf = *(const f16x8*)(bb + tt * 512 + lane * 8);
            f32x16 zz = {0.f,0.f,0.f,0.f,0.f,0.f,0.f,0.f,0.f,0.f,0.f,0.f,0.f,0.f,0.f,0.f};
            f32x16 a0 = __builtin_amdgcn_mfma_f32_32x32x16_f16(af0, bf, zz, 0, 0, 0);
            f32x16 a1 = __builtin_amdgcn_mfma_f32_32x32x16_f16(af1, bf, zz, 0, 0, 0);
#pragma unroll
            for (int r = 0; r < 16; ++r) {
                rm0[r] = fminf(rm0[r], a0[r]);
                rm1[r] = fminf(rm1[r], a1[r]);
            }
        }
        __syncthreads();
        if (c + 1 < NCH_) WRITEV((c + 1) & 1);
        __syncthreads();
    }
    // reduce over the 32 cols (lanes within each half) -> per-row threshold
    f32x16 th0, th1;
#pragma unroll
    for (int r = 0; r < 16; ++r) {
        float v0 = rm0[r], v1 = rm1[r];
        v0 = fminf(v0, __shfl_xor(v0, 1));  v1 = fminf(v1, __shfl_xor(v1, 1));
        v0 = fminf(v0, __shfl_xor(v0, 2));  v1 = fminf(v1, __shfl_xor(v1, 2));
        v0 = fminf(v0, __shfl_xor(v0, 4));  v1 = fminf(v1, __shfl_xor(v1, 4));
        v0 = fminf(v0, __shfl_xor(v0, 8));  v1 = fminf(v1, __shfl_xor(v1, 8));
        v0 = fminf(v0, __shfl_xor(v0, 16)); v1 = fminf(v1, __shfl_xor(v1, 16));
        th0[r] = v0 + EPS2_; th1[r] = v1 + EPS2_;
    }

    // ---------------- pass B: exact refine ----------------
    const float4* kcb = kco + (size_t)b * M_;
    const float* ub = unk + (size_t)b * N_ * 3;
    const int rloc0 = w * 64 + ((lane >> 5) << 2);   // + (r&3)+8*(r>>2) [+32 for af1]

    STAGEV(0); WRITEV(0);
    __syncthreads();
    for (int c = 0; c < NCH_; ++c) {
        if (c + 1 < NCH_) STAGEV(c + 1);
        const u16* bb = sB[c & 1];
#pragma unroll 2
        for (int tt = 0; tt < CH_; ++tt) {
            f16x8 bf = *(const f16x8*)(bb + tt * 512 + lane * 8);
            f32x16 zz = {0.f,0.f,0.f,0.f,0.f,0.f,0.f,0.f,0.f,0.f,0.f,0.f,0.f,0.f,0.f,0.f};
            f32x16 a0 = __builtin_amdgcn_mfma_f32_32x32x16_f16(af0, bf, zz, 0, 0, 0);
            f32x16 a1 = __builtin_amdgcn_mfma_f32_32x32x16_f16(af1, bf, zz, 0, 0, 0);
            unsigned long long m = 0;
#pragma unroll
            for (int r = 0; r < 16; ++r)
                m |= __ballot(a0[r] <= th0[r]) | __ballot(a1[r] <= th1[r]);
            if (m) {                                 // wave-uniform, rarely taken
                int j = (c * CH_ + tt) * 32 + (lane & 31);
                float4 kc = kcb[j];
#pragma unroll
                for (int r = 0; r < 16; ++r) {
                    if (a0[r] <= th0[r]) {
                        int rl = rloc0 + (r & 3) + 8 * (r >> 2);
                        const float* up = ub + (size_t)(rowbase + rl) * 3;
                        float x = up[0], y = up[1], zc = up[2];
                        float uq = sq3_np(x, y, zc);
                        float dot = dot3_fma(x, kc.x, y, kc.y, zc, kc.z);
                        float d = __fadd_rn(fmaf(-2.0f, dot, uq), kc.w);
                        u32 db = __float_as_uint(d);
                        db = (db & 0x80000000u) ? ~db : (db | 0x80000000u);
                        atomicMin(&cand[rl], ((unsigned long long)db << 32) | (u32)j);
                    }
                    if (a1[r] <= th1[r]) {
                        int rl = rloc0 + 32 + (r & 3) + 8 * (r >> 2);
                        const float* up = ub + (size_t)(rowbase + rl) * 3;
                        float x = up[0], y = up[1], zc = up[2];
                        float uq = sq3_np(x, y, zc);
                        float dot = dot3_fma(x, kc.x, y, kc.y, zc, kc.z);
                        float d = __fadd_rn(fmaf(-2.0f, dot, uq), kc.w);
                        u32 db = __float_as_uint(d);
                        db = (db & 0x80000000u) ? ~db : (db | 0x80000000u);
                        atomicMin(&cand[rl], ((unsigned long long)db << 32) | (u32)j);
                    }
                }
            }
        }
        __syncthreads();
        if (c + 1 < NCH_) WRITEV((c + 1) & 1);
        __syncthreads();
    }
    idx[b * N_ + rowbase + t] = (int)(u32)(cand[t] & 0xFFFFFFFFu);
#undef STAGEV
#undef WRITEV
}

// ------------------------------------------- transpose known_feats -> (b,m,c) bf16
__global__ __launch_bounds__(256) void k_tr_kf(const float* __restrict__ kf,
                                               u16* __restrict__ kfT) {
    __shared__ float lt[64][65];
    const int t = threadIdx.x, b = blockIdx.z;
    const int j0 = blockIdx.x * 64, c0 = blockIdx.y * 64;
    const int jl = t & 63, cl4 = t >> 6;
#pragma unroll
    for (int p = 0; p < 16; ++p) {
        int c = c0 + cl4 + p * 4;
        lt[cl4 + p * 4][jl] = kf[((size_t)(b * C2_ + c)) * M_ + j0 + jl];
    }
    __syncthreads();
    const int cl = t & 63, jr4 = t >> 6;
#pragma unroll
    for (int p = 0; p < 16; ++p) {
        int j = j0 + jr4 + p * 4;
        kfT[((size_t)(b * M_ + j)) * C2_ + c0 + cl] = f2bf(lt[cl][jr4 + p * 4]);
    }
}

// ------------------------------- transpose unknow_feats into newF[...,256:384) bf16
__global__ __launch_bounds__(256) void k_tr_uf(const float* __restrict__ uf,
                                               u16* __restrict__ newF) {
    __shared__ float lt[64][65];
    const int t = threadIdx.x, b = blockIdx.z;
    const int i0 = blockIdx.x * 64, c0 = blockIdx.y * 64;
    const int il = t & 63, cl4 = t >> 6;
#pragma unroll
    for (int p = 0; p < 16; ++p) {
        int c = c0 + cl4 + p * 4;
        lt[cl4 + p * 4][il] = uf[((size_t)(b * C1_ + c)) * N_ + i0 + il];
    }
    __syncthreads();
    const int cl = t & 63, ir4 = t >> 6;
#pragma unroll
    for (int p = 0; p < 16; ++p) {
        int i = i0 + ir4 + p * 4;
        newF[((size_t)(b * N_ + i)) * K1_ + C2_ + c0 + cl] = f2bf(lt[cl][ir4 + p * 4]);
    }
}

// ------------------------------------ gather kfT rows into newF[...,0:256) (dense)
__global__ __launch_bounds__(256) void k_gather(const u16* __restrict__ kfT,
                                                const int* __restrict__ idx,
                                                u16* __restrict__ newF) {
    const int t = threadIdx.x, b = blockIdx.y;
    const int il = t >> 5, qq = t & 31;
    const int i = blockIdx.x * 8 + il;
    const int j = idx[b * N_ + i];
    const uint4* src = (const uint4*)(kfT + ((size_t)(b * M_ + j)) * C2_) + qq;
    uint4* dst = (uint4*)(newF + ((size_t)(b * N_ + i)) * K1_) + qq;
    *dst = *src;
}

// ---------------------------------------------------------------- GEMM1
// y1[b][i][o] (bf16) = newF[b][i][:] . w1[o][:]   tiles 128x128, BK=32
__global__ __launch_bounds__(256) void k_gemm1(const u16* __restrict__ newF,
                                               const float* __restrict__ w1,
                                               u16* __restrict__ y1) {
    __shared__ u16 As[128 * 40];
    __shared__ u16 Bs[128 * 40];
    const int t = threadIdx.x, b = blockIdx.z;
    const int i0 = blockIdx.x * 128, o0 = blockIdx.y * 128;
    const int lane = t & 63, wv = t >> 6, wr = wv >> 1, wc = wv & 1;
    const int col = lane & 15, q = lane >> 4;

    const int rA0 = t >> 2, sA0 = t & 3;   // +256 => row+64, same sub
    const u16* aS0 = newF + ((size_t)(b * N_ + i0 + rA0)) * K1_ + sA0 * 8;
    const u16* aS1 = aS0 + (size_t)64 * K1_;
    const float* bS0 = w1 + (size_t)(o0 + rA0) * K1_ + sA0 * 8;
    const float* bS1 = bS0 + (size_t)64 * K1_;
    u16* aD0 = &As[rA0 * 40 + sA0 * 8];
    u16* aD1 = aD0 + 64 * 40;
    u16* bD0 = &Bs[rA0 * 40 + sA0 * 8];
    u16* bD1 = bD0 + 64 * 40;

    f32x4 acc[4][4];
#pragma unroll
    for (int m = 0; m < 4; ++m)
#pragma unroll
        for (int n = 0; n < 4; ++n) acc[m][n] = (f32x4){0.f, 0.f, 0.f, 0.f};

    uint4 a0 = *(const uint4*)aS0, a1 = *(const uint4*)aS1;
    float4 f00 = *(const float4*)bS0, f01 = *(const float4*)(bS0 + 4);
    float4 f10 = *(const float4*)bS1, f11 = *(const float4*)(bS1 + 4);

    for (int ks = 0; ks < 12; ++ks) {
        __syncthreads();
        *(uint4*)aD0 = a0; *(uint4*)aD1 = a1;
        *(uint4*)bD0 = pack8(f00, f01); *(uint4*)bD1 = pack8(f10, f11);
        __syncthreads();
        if (ks < 11) {
            int ko = (ks + 1) * 32;
            a0 = *(const uint4*)(aS0 + ko); a1 = *(const uint4*)(aS1 + ko);
            f00 = *(const float4*)(bS0 + ko); f01 = *(const float4*)(bS0 + ko + 4);
            f10 = *(const float4*)(bS1 + ko); f11 = *(const float4*)(bS1 + ko + 4);
        }
        const u16* ap = &As[(wr * 64 + col) * 40 + q * 8];
        const u16* bp = &Bs[(wc * 64 + col) * 40 + q * 8];
        bf16x8 af[4], bfr[4];
#pragma unroll
        for (int m = 0; m < 4; ++m) af[m] = *(const bf16x8*)(ap + m * 640);
#pragma unroll
        for (int n = 0; n < 4; ++n) bfr[n] = *(const bf16x8*)(bp + n * 640);
#pragma unroll
        for (int m = 0; m < 4; ++m)
#pragma unroll
            for (int n = 0; n < 4; ++n)
                acc[m][n] = __builtin_amdgcn_mfma_f32_16x16x32_bf16(af[m], bfr[n], acc[m][n], 0, 0, 0);
    }
#pragma unroll
    for (int m = 0; m < 4; ++m)
#pragma unroll
        for (int n = 0; n < 4; ++n) {
            int go = o0 + wc * 64 + n * 16 + col;
#pragma unroll
            for (int r = 0; r < 4; ++r) {
                int gi = i0 + wr * 64 + m * 16 + q * 4 + r;
                y1[((size_t)(b * N_ + gi)) * O1_ + go] = f2bf(acc[m][n][r]);
            }
        }
}

// ------------------------------------------------- BN stats over y1 (bf16, 256 ch)
__global__ __launch_bounds__(256) void k_stats_bf16(const u16* __restrict__ y1,
                                                    float* __restrict__ sum,
                                                    float* __restrict__ sq) {
    const int t = threadIdx.x;
    const int row0 = blockIdx.x * 1024;
    float s = 0.f, qq = 0.f;
    for (int r = 0; r < 1024; ++r) {
        float v = bf2f(y1[((size_t)(row0 + r)) * O1_ + t]);
        s += v; qq = fmaf(v, v, qq);
    }
    atomicAdd(&sum[t], s);
    atomicAdd(&sq[t], qq);
}

// ------------------------------------------------- BN stats over y2 (f32, 128 ch)
__global__ __launch_bounds__(256) void k_stats_f32(const float* __restrict__ y2,
                                                   float* __restrict__ sum,
                                                   float* __restrict__ sq) {
    const int t = threadIdx.x;
    const int o = t & 127, h = t >> 7;
    const int row0 = blockIdx.x * 1024;
    float s = 0.f, qq = 0.f;
    for (int r = 0; r < 512; ++r) {
        float v = y2[((size_t)(row0 + r * 2 + h)) * O2_ + o];
        s += v; qq = fmaf(v, v, qq);
    }
    atomicAdd(&sum[o], s);
    atomicAdd(&sq[o], qq);
}

__global__ void k_bn_fin(const float* __restrict__ sum, const float* __restrict__ sq,
                         const float* __restrict__ gamma, const float* __restrict__ beta,
                         float* __restrict__ scale, float* __restrict__ bias,
                         int C, float invN) {
    int t = threadIdx.x;
    if (t < C) {
        float mean = sum[t] * invN;
        float var = sq[t] * invN - mean * mean;
        float rs = rsqrtf(var + 1e-5f);
        float sc = gamma[t] * rs;
        scale[t] = sc;
        bias[t] = beta[t] - mean * sc;
    }
}

// ---------------------------------------------------------------- GEMM2
// y2[b][i][o] (f32) = relu(bn1(y1))[b][i][:] . w2[o][:]  (BN1 fused in A-staging)
__global__ __launch_bounds__(256) void k_gemm2(const u16* __restrict__ y1,
                                               const float* __restrict__ w2,
                                               const float* __restrict__ s1,
                                               const float* __restrict__ b1,
                                               float* __restrict__ y2) {
    __shared__ u16 As[128 * 40];
    __shared__ u16 Bs[128 * 40];
    const int t = threadIdx.x, b = blockIdx.z;
    const int i0 = blockIdx.x * 128;
    const int lane = t & 63, wv = t >> 6, wr = wv >> 1, wc = wv & 1;
    const int col = lane & 15, q = lane >> 4;

    const int rA0 = t >> 2, sA0 = t & 3;
    const u16* aS0 = y1 + ((size_t)(b * N_ + i0 + rA0)) * O1_ + sA0 * 8;
    const u16* aS1 = aS0 + (size_t)64 * O1_;
    const float* bS0 = w2 + (size_t)rA0 * O1_ + sA0 * 8;
    const float* bS1 = bS0 + (size_t)64 * O1_;
    u16* aD0 = &As[rA0 * 40 + sA0 * 8];
    u16* aD1 = aD0 + 64 * 40;
    u16* bD0 = &Bs[rA0 * 40 + sA0 * 8];
    u16* bD1 = bD0 + 64 * 40;

    f32x4 acc[4][4];
#pragma unroll
    for (int m = 0; m < 4; ++m)
#pragma unroll
        for (int n = 0; n < 4; ++n) acc[m][n] = (f32x4){0.f, 0.f, 0.f, 0.f};

    uint4 a0 = *(const uint4*)aS0, a1 = *(const uint4*)aS1;
    float4 f00 = *(const float4*)bS0, f01 = *(const float4*)(bS0 + 4);
    float4 f10 = *(const float4*)bS1, f11 = *(const float4*)(bS1 + 4);

    for (int ks = 0; ks < 8; ++ks) {
        int oc = ks * 32 + sA0 * 8;
        float4 sc0 = *(const float4*)(s1 + oc), sc1 = *(const float4*)(s1 + oc + 4);
        float4 bb0 = *(const float4*)(b1 + oc), bb1 = *(const float4*)(b1 + oc + 4);
        uint4 h0, h1;
        {
            const u16* hs = (const u16*)&a0;
            float v[8];
            v[0] = fmaxf(fmaf(bf2f(hs[0]), sc0.x, bb0.x), 0.f);
            v[1] = fmaxf(fmaf(bf2f(hs[1]), sc0.y, bb0.y), 0.f);
            v[2] = fmaxf(fmaf(bf2f(hs[2]), sc0.z, bb0.z), 0.f);
            v[3] = fmaxf(fmaf(bf2f(hs[3]), sc0.w, bb0.w), 0.f);
            v[4] = fmaxf(fmaf(bf2f(hs[4]), sc1.x, bb1.x), 0.f);
            v[5] = fmaxf(fmaf(bf2f(hs[5]), sc1.y, bb1.y), 0.f);
            v[6] = fmaxf(fmaf(bf2f(hs[6]), sc1.z, bb1.z), 0.f);
            v[7] = fmaxf(fmaf(bf2f(hs[7]), sc1.w, bb1.w), 0.f);
            h0.x = pack2(v[0], v[1]); h0.y = pack2(v[2], v[3]);
            h0.z = pack2(v[4], v[5]); h0.w = pack2(v[6], v[7]);
        }
        {
            const u16* hs = (const u16*)&a1;
            float v[8];
            v[0] = fmaxf(fmaf(bf2f(hs[0]), sc0.x, bb0.x), 0.f);
            v[1] = fmaxf(fmaf(bf2f(hs[1]), sc0.y, bb0.y), 0.f);
            v[2] = fmaxf(fmaf(bf2f(hs[2]), sc0.z, bb0.z), 0.f);
            v[3] = fmaxf(fmaf(bf2f(hs[3]), sc0.w, bb0.w), 0.f);
            v[4] = fmaxf(fmaf(bf2f(hs[4]), sc1.x, bb1.x), 0.f);
            v[5] = fmaxf(fmaf(bf2f(hs[5]), sc1.y, bb1.y), 0.f);
            v[6] = fmaxf(fmaf(bf2f(hs[6]), sc1.z, bb1.z), 0.f);
            v[7] = fmaxf(fmaf(bf2f(hs[7]), sc1.w, bb1.w), 0.f);
            h1.x = pack2(v[0], v[1]); h1.y = pack2(v[2], v[3]);
            h1.z = pack2(v[4], v[5]); h1.w = pack2(v[6], v[7]);
        }
        __syncthreads();
        *(uint4*)aD0 = h0; *(uint4*)aD1 = h1;
        *(uint4*)bD0 = pack8(f00, f01); *(uint4*)bD1 = pack8(f10, f11);
        __syncthreads();
        if (ks < 7) {
            int ko = (ks + 1) * 32;
            a0 = *(const uint4*)(aS0 + ko); a1 = *(const uint4*)(aS1 + ko);
            f00 = *(const float4*)(bS0 + ko); f01 = *(const float4*)(bS0 + ko + 4);
            f10 = *(const float4*)(bS1 + ko); f11 = *(const float4*)(bS1 + ko + 4);
        }
        const u16* ap = &As[(wr * 64 + col) * 40 + q * 8];
        const u16* bp = &Bs[(wc * 64 + col) * 40 + q * 8];
        bf16x8 af[4], bfr[4];
#pragma unroll
        for (int m = 0; m < 4; ++m) af[m] = *(const bf16x8*)(ap + m * 640);
#pragma unroll
        for (int n = 0; n < 4; ++n) bfr[n] = *(const bf16x8*)(bp + n * 640);
#pragma unroll
        for (int m = 0; m < 4; ++m)
#pragma unroll
            for (int n = 0; n < 4; ++n)
                acc[m][n] = __builtin_amdgcn_mfma_f32_16x16x32_bf16(af[m], bfr[n], acc[m][n], 0, 0, 0);
    }
#pragma unroll
    for (int m = 0; m < 4; ++m)
#pragma unroll
        for (int n = 0; n < 4; ++n) {
            int go = wc * 64 + n * 16 + col;
#pragma unroll
            for (int r = 0; r < 4; ++r) {
                int gi = i0 + wr * 64 + m * 16 + q * 4 + r;
                y2[((size_t)(b * N_ + gi)) * O2_ + go] = acc[m][n][r];
            }
        }
}

// ---------------------------- BN2 affine + ReLU + transpose (b,i,o)->(b,o,i) out
__global__ __launch_bounds__(256) void k_out(const float* __restrict__ y2,
                                             const float* __restrict__ s2,
                                             const float* __restrict__ b2,
                                             float* __restrict__ out) {
    __shared__ float lt[64 * 65];
    const int t = threadIdx.x, b = blockIdx.z;
    const int i0 = blockIdx.x * 64, o0 = blockIdx.y * 64;
    const int oc = t & 63, ir4 = t >> 6;
    const float sc = s2[o0 + oc], bs = b2[o0 + oc];
#pragma unroll
    for (int p = 0; p < 16; ++p) {
        int i = i0 + ir4 + p * 4;
        float v = y2[((size_t)(b * N_ + i)) * O2_ + o0 + oc];
        lt[oc * 65 + ir4 + p * 4] = fmaxf(fmaf(v, sc, bs), 0.f);
    }
    __syncthreads();
    const int il = t & 63, or4 = t >> 6;
#pragma unroll
    for (int p = 0; p < 16; ++p) {
        int o = o0 + or4 + p * 4;
        out[((size_t)(b * O2_ + o)) * N_ + i0 + il] = lt[(or4 + p * 4) * 65 + il];
    }
}

extern "C" void kernel_launch(void* const* d_in, const int* in_sizes, int n_in,
                              void* d_out, int out_size, void* d_ws, size_t ws_size,
                              hipStream_t stream) {
    const float* unknown = (const float*)d_in[0];
    const float* known   = (const float*)d_in[1];
    const float* uf      = (const float*)d_in[2];
    const float* kf      = (const float*)d_in[3];
    const float* w1      = (const float*)d_in[4];
    const float* g1      = (const float*)d_in[5];
    const float* be1     = (const float*)d_in[6];
    const float* w2      = (const float*)d_in[7];
    const float* g2      = (const float*)d_in[8];
    const float* be2     = (const float*)d_in[9];
    float* out = (float*)d_out;

    char* w = (char*)d_ws;
    // stats block (zeroed each call): bn1_sum[256] bn1_sq[256] bn2_sum[128] bn2_sq[128]
    float* bn1_sum = (float*)w;
    float* bn1_sq  = bn1_sum + 256;
    float* bn2_sum = bn1_sq + 256;
    float* bn2_sq  = bn2_sum + 128;
    float* s1 = (float*)(w + 4096);     // 256
    float* b1 = s1 + 256;               // 256
    float* s2 = b1 + 256;               // 128
    float* b2 = s2 + 128;               // 128
    int* idx = (int*)(w + 8192);                        // 512 KiB
    u16* newF = (u16*)(w + 532480);                     // (B,n,384) bf16 = 100.7 MB
    float* y2 = (float*)(w + 532480);                   // alias (newF dead by GEMM2)
    size_t R2 = 532480 + 100663296ULL;
    // NN scratch (dead before y1 is written):
    u16*   Aprep = (u16*)(w + R2);                      // 4 MiB (4096 tiles * 1KB)
    u16*   Bprep = (u16*)(w + R2 + 4194304ULL);         // 1 MiB (1024 tiles * 1KB)
    float4* kco  = (float4*)(w + R2 + 5242880ULL);      // 512 KiB
    u16*  kfT = (u16*)(w + R2 + 16777216ULL);           // 16.7MB (dead before y1)
    u16*   y1 = (u16*)(w + R2);                         // (B,n,256) bf16 = 67 MB

    hipMemsetAsync(w, 0, 3072, stream);   // zero BN accumulators

    k_prep_u<<<512, 256, 0, stream>>>(unknown, Aprep);
    k_prep_k<<<128, 256, 0, stream>>>(known, Bprep, kco);
    k_nn<<<dim3(256, B_), 256, 0, stream>>>(Aprep, Bprep, unknown, kco, idx);
    k_tr_kf<<<dim3(256, 4, 2), 256, 0, stream>>>(kf, kfT);
    k_tr_uf<<<dim3(1024, 2, 2), 256, 0, stream>>>(uf, newF);
    k_gather<<<dim3(8192, 2), 256, 0, stream>>>(kfT, idx, newF);
    k_gemm1<<<dim3(512, 2, 2), 256, 0, stream>>>(newF, w1, y1);
    k_stats_bf16<<<128, 256, 0, stream>>>(y1, bn1_sum, bn1_sq);
    k_bn_fin<<<1, 256, 0, stream>>>(bn1_sum, bn1_sq, g1, be1, s1, b1, 256, 1.f / 131072.f);
    k_gemm2<<<dim3(512, 1, 2), 256, 0, stream>>>(y1, w2, s1, b1, y2);
    k_stats_f32<<<128, 256, 0, stream>>>(y2, bn2_sum, bn2_sq);
    k_bn_fin<<<1, 256, 0, stream>>>(bn2_sum, bn2_sq, g2, be2, s2, b2, 128, 1.f / 131072.f);
    k_out<<<dim3(1024, 2, 2), 256, 0, stream>>>(y2, s2, b2, out);
}

// Round 3
// 618.552 us; speedup vs baseline: 1.4603x; 1.1593x over previous
//
#include <hip/hip_runtime.h>

typedef unsigned short u16;
typedef unsigned int u32;
typedef __bf16 bf16x8 __attribute__((ext_vector_type(8)));
typedef _Float16 f16;
typedef _Float16 f16x8 __attribute__((ext_vector_type(8)));
typedef float f32x4 __attribute__((ext_vector_type(4)));
typedef float f32x16 __attribute__((ext_vector_type(16)));

#define B_ 2
#define N_ 65536
#define M_ 16384
#define C1_ 128
#define C2_ 256
#define K1_ 384   // C1+C2
#define O1_ 256   // mlp[1]
#define O2_ 128   // mlp[2]
#define JT_ 512       // 32-wide j-tiles per batch (M_/32)
#define CH_ 16        // j-tiles per LDS chunk (16 KB)
#define NCH_ ((JT_/2)/CH_)   // chunks per j-half = 16
#define EPS2_ 6.0e-3f // 2*eps certified ordering slack (verified rounds 1-2)
#define TFIN_ 1.25e-4f // threshold-fold inflation >= worst-case f16 hi/lo fold error

__device__ __forceinline__ u16 f2bf(float f) {
    u32 u = __float_as_uint(f);
    u32 r = (u + 0x7FFFu + ((u >> 16) & 1u)) >> 16;   // RNE
    return (u16)r;
}
__device__ __forceinline__ float bf2f(u16 h) {
    return __uint_as_float(((u32)h) << 16);
}
__device__ __forceinline__ u32 pack2(float lo, float hi) {
    return (u32)f2bf(lo) | ((u32)f2bf(hi) << 16);
}
__device__ __forceinline__ uint4 pack8(float4 a, float4 b) {
    uint4 r;
    r.x = pack2(a.x, a.y); r.y = pack2(a.z, a.w);
    r.z = pack2(b.x, b.y); r.w = pack2(b.z, b.w);
    return r;
}
__device__ __forceinline__ u16 h2u(f16 h) {
    union { f16 h; u16 u; } c; c.h = h; return c.u;
}

// Exact-IEEE fp32 mul with an optimization barrier so the backend can NEVER
// contract it into an FMA (HIP default is -ffp-contract=fast).
__device__ __forceinline__ float mul_rn(float a, float b) {
    float p = __fmul_rn(a, b);
    asm volatile("" : "+v"(p));
    return p;
}
// u2/k2: elementwise-square (each product rounded) + ascending reduce
__device__ __forceinline__ float sq3_np(float x, float y, float z) {
    return __fadd_rn(__fadd_rn(mul_rn(x, x), mul_rn(y, y)), mul_rn(z, z));
}
// Eigen/XLA gebp K=3 dot: ascending k, FMA accumulate into rounded first product
__device__ __forceinline__ float dot3_fma(float a0, float b0, float a1, float b1,
                                          float a2, float b2) {
    return fmaf(a2, b2, fmaf(a1, b1, mul_rn(a0, b0)));
}

// ============================== NN search: 32x32x16 MFMA filter + exact refine
// key val_ij = k2_j - 2*dot_ij via mfma_f32_32x32x16_f16 (layout verified r2).
// K-slots: 0-8 split coords (A has -2 folded), 9-10 = k2 hi/lo via A=1.0,
// 11-12: pass A -> A=0 (inactive); pass B -> A=-(thr+TFIN_) hi/lo, B=1.0, so
// the MFMA emits val - thr' directly. Effective threshold thr' in
// [thr+~5e-5, thr+~2e-4] >= thr  => candidate SUPERSET of the certified set
// => exact-refine still reproduces the reference argmin bit-exactly.
// j-range is split in halves (blockIdx.y); each half does its own pass A
// (rowmin over its half) + pass B (exact d, packed (monot(d)<<32|j) LDS
// atomicMin); k_nn_merge takes the min of the two packed keys (lower half
// always has smaller j => ascending-j first-wins preserved).

__global__ __launch_bounds__(256) void k_prep_u(const float* __restrict__ unk,
                                                u16* __restrict__ Aprep) {
    int g = blockIdx.x * 256 + threadIdx.x;          // over B*N
    const float* up = unk + (size_t)g * 3;
    float tx = -2.f * up[0], ty = -2.f * up[1], tz = -2.f * up[2];
    f16 xh = (f16)tx; f16 xl = (f16)(tx - (float)xh);
    f16 yh = (f16)ty; f16 yl = (f16)(ty - (float)yh);
    f16 zh = (f16)tz; f16 zl = (f16)(tz - (float)zh);
    u16 lo[8] = {h2u(xh), h2u(xh), h2u(xl), h2u(yh), h2u(yh), h2u(yl), h2u(zh), h2u(zh)};
    u16 hi[8] = {h2u(zl), 0x3C00u, 0x3C00u, 0, 0, 0, 0, 0};
    u16* tb = Aprep + ((size_t)(g >> 5)) * 512;      // tile = 64 lanes * 8 u16
    int r = g & 31;
    *(uint4*)(tb + r * 8) = *(uint4*)lo;
    *(uint4*)(tb + (r + 32) * 8) = *(uint4*)hi;
}

__global__ __launch_bounds__(256) void k_prep_k(const float* __restrict__ kn,
                                                u16* __restrict__ Bprep,
                                                float4* __restrict__ kco) {
    int g = blockIdx.x * 256 + threadIdx.x;          // over B*M
    const float* kp = kn + (size_t)g * 3;
    float x = kp[0], y = kp[1], z = kp[2];
    float qv = sq3_np(x, y, z);                       // EXACT ref k2 sequence
    f16 xh = (f16)x; f16 xl = (f16)(x - (float)xh);
    f16 yh = (f16)y; f16 yl = (f16)(y - (float)yh);
    f16 zh = (f16)z; f16 zl = (f16)(z - (float)zh);
    f16 qh = (f16)qv; f16 ql = (f16)(qv - (float)qh);
    u16 lo[8] = {h2u(xh), h2u(xl), h2u(xh), h2u(yh), h2u(yl), h2u(yh), h2u(zh), h2u(zl)};
    // slots 11,12 = 1.0 so pass B's A-side -thr hi/lo ride the same MFMA
    u16 hi[8] = {h2u(zh), h2u(qh), h2u(ql), 0x3C00u, 0x3C00u, 0, 0, 0};
    u16* tb = Bprep + ((size_t)(g >> 5)) * 512;
    int r = g & 31;
    *(uint4*)(tb + r * 8) = *(uint4*)lo;
    *(uint4*)(tb + (r + 32) * 8) = *(uint4*)hi;
    kco[g] = make_float4(x, y, z, qv);
}

__global__ __launch_bounds__(256, 4) void k_nn(
        const u16* __restrict__ Aprep, const u16* __restrict__ Bprep,
        const float* __restrict__ unk, const float4* __restrict__ kco,
        unsigned long long* __restrict__ pc) {
    __shared__ u16 sB[2][CH_ * 512];                 // 2 x 16 KB
    __shared__ unsigned long long cand[256];
    __shared__ float thrS[256];
    const int t = threadIdx.x;
    const int half = blockIdx.y, b = blockIdx.z;
    const int lane = t & 63, w = t >> 6;
    const int rowbase = blockIdx.x * 256;            // 256 rows per block
    const u16* at = Aprep + (((size_t)(b * N_ + rowbase + w * 64)) >> 5) * 512;
    f16x8 af0 = *(const f16x8*)(at + lane * 8);      // row-tile 0 (32 rows)
    f16x8 af1 = *(const f16x8*)(at + 512 + lane * 8);// row-tile 1
    const u16* Bsrc = Bprep + ((size_t)b * JT_ + (size_t)half * (JT_ / 2)) * 512;
    cand[t] = ~0ULL;

    uint4 vs0, vs1, vs2, vs3;
#define STAGEV(c) { const u16* sp = Bsrc + (size_t)(c) * (CH_ * 512) + t * 8;  \
    vs0 = *(const uint4*)sp;          vs1 = *(const uint4*)(sp + 2048);        \
    vs2 = *(const uint4*)(sp + 4096); vs3 = *(const uint4*)(sp + 6144); }
#define WRITEV(bi) { u16* dp = &sB[bi][t * 8];                                 \
    *(uint4*)dp = vs0;          *(uint4*)(dp + 2048) = vs1;                    \
    *(uint4*)(dp + 4096) = vs2; *(uint4*)(dp + 6144) = vs3; }

    const f32x16 zz = {0.f,0.f,0.f,0.f,0.f,0.f,0.f,0.f,0.f,0.f,0.f,0.f,0.f,0.f,0.f,0.f};

    // ---------------- pass A: rowmin over this j-half ----------------
    f32x16 rm0, rm1;
#pragma unroll
    for (int r = 0; r < 16; ++r) { rm0[r] = 3.4e38f; rm1[r] = 3.4e38f; }

    STAGEV(0); WRITEV(0);
    __syncthreads();
    for (int c = 0; c < NCH_; ++c) {
        if (c + 1 < NCH_) STAGEV(c + 1);
        const u16* bb = sB[c & 1];
#pragma unroll 2
        for (int tp = 0; tp < CH_; tp += 2) {       // paired j-tiles -> v_min3
            f16x8 bf0 = *(const f16x8*)(bb + tp * 512 + lane * 8);
            f16x8 bf1 = *(const f16x8*)(bb + tp * 512 + 512 + lane * 8);
            f32x16 a  = __builtin_amdgcn_mfma_f32_32x32x16_f16(af0, bf0, zz, 0, 0, 0);
            f32x16 ca = __builtin_amdgcn_mfma_f32_32x32x16_f16(af0, bf1, zz, 0, 0, 0);
#pragma unroll
            for (int r = 0; r < 16; ++r)
                rm0[r] = fminf(fminf(rm0[r], a[r]), ca[r]);
            a  = __builtin_amdgcn_mfma_f32_32x32x16_f16(af1, bf0, zz, 0, 0, 0);
            ca = __builtin_amdgcn_mfma_f32_32x32x16_f16(af1, bf1, zz, 0, 0, 0);
#pragma unroll
            for (int r = 0; r < 16; ++r)
                rm1[r] = fminf(fminf(rm1[r], a[r]), ca[r]);
        }
        __syncthreads();
        if (c + 1 < NCH_) WRITEV((c + 1) & 1);
        __syncthreads();
    }

    STAGEV(0);   // prefetch pass-B chunk 0; HBM/L2 latency hides under reduce

    // reduce over the 32 cols -> per-row thresholds into LDS
#pragma unroll
    for (int r = 0; r < 16; ++r) {
        float v0 = rm0[r], v1 = rm1[r];
        v0 = fminf(v0, __shfl_xor(v0, 1));  v1 = fminf(v1, __shfl_xor(v1, 1));
        v0 = fminf(v0, __shfl_xor(v0, 2));  v1 = fminf(v1, __shfl_xor(v1, 2));
        v0 = fminf(v0, __shfl_xor(v0, 4));  v1 = fminf(v1, __shfl_xor(v1, 4));
        v0 = fminf(v0, __shfl_xor(v0, 8));  v1 = fminf(v1, __shfl_xor(v1, 8));
        v0 = fminf(v0, __shfl_xor(v0, 16)); v1 = fminf(v1, __shfl_xor(v1, 16));
        if ((lane & 31) == 0) {
            int rl = w * 64 + ((lane >> 5) << 2) + (r & 3) + 8 * (r >> 2);
            thrS[rl] = v0 + EPS2_;
            thrS[rl + 32] = v1 + EPS2_;
        }
    }
    __syncthreads();
    // patch A fragments: k-slots 11,12 (lanes>=32, elems 3,4) = -(thr+TFIN_) hi/lo
    if (lane >= 32) {
        float tf0 = thrS[w * 64 + (lane & 31)] + TFIN_;
        float tf1 = thrS[w * 64 + 32 + (lane & 31)] + TFIN_;
        f16 h0 = (f16)(-tf0);
        af0[3] = h0; af0[4] = (f16)(-tf0 - (float)h0);
        f16 h1 = (f16)(-tf1);
        af1[3] = h1; af1[4] = (f16)(-tf1 - (float)h1);
    }
    WRITEV(0);
    __syncthreads();

    // ---------------- pass B: exact refine (MFMA emits val - thr') ----------
    const float4* kcb = kco + (size_t)b * M_;
    const float* ub = unk + (size_t)b * N_ * 3;
    const int rloc0 = w * 64 + ((lane >> 5) << 2);   // + (r&3)+8*(r>>2) [+32 rt1]
    const int jb0 = half * (M_ / 2);

    for (int c = 0; c < NCH_; ++c) {
        if (c + 1 < NCH_) STAGEV(c + 1);
        const u16* bb = sB[c & 1];
#pragma unroll 2
        for (int tt = 0; tt < CH_; ++tt) {
            f16x8 bf = *(const f16x8*)(bb + tt * 512 + lane * 8);
            f32x16 a0 = __builtin_amdgcn_mfma_f32_32x32x16_f16(af0, bf, zz, 0, 0, 0);
            f32x16 a1 = __builtin_amdgcn_mfma_f32_32x32x16_f16(af1, bf, zz, 0, 0, 0);
            // sign test via min3 tree: a<=0 iff candidate (thr folded into MFMA)
            float u0 = fminf(fminf(a0[0], a0[1]), a0[2]);
            float u1 = fminf(fminf(a0[3], a0[4]), a0[5]);
            float u2 = fminf(fminf(a0[6], a0[7]), a0[8]);
            float u3 = fminf(fminf(a0[9], a0[10]), a0[11]);
            float u4 = fminf(fminf(a0[12], a0[13]), a0[14]);
            float tm0 = fminf(fminf(fminf(u0, u1), a0[15]), fminf(fminf(u2, u3), u4));
            float w0 = fminf(fminf(a1[0], a1[1]), a1[2]);
            float w1 = fminf(fminf(a1[3], a1[4]), a1[5]);
            float w2 = fminf(fminf(a1[6], a1[7]), a1[8]);
            float w3 = fminf(fminf(a1[9], a1[10]), a1[11]);
            float w4 = fminf(fminf(a1[12], a1[13]), a1[14]);
            float tm1 = fminf(fminf(fminf(w0, w1), a1[15]), fminf(fminf(w2, w3), w4));
            unsigned long long m = __ballot(tm0 <= 0.f) | __ballot(tm1 <= 0.f);
            if (m) {                                 // wave-uniform, rarely taken
                int j = jb0 + (c * CH_ + tt) * 32 + (lane & 31);
                float4 kc = kcb[j];
#pragma unroll
                for (int r = 0; r < 16; ++r) {
                    if (a0[r] <= 0.f) {
                        int rl = rloc0 + (r & 3) + 8 * (r >> 2);
                        const float* up = ub + (size_t)(rowbase + rl) * 3;
                        float x = up[0], y = up[1], zc = up[2];
                        float uq = sq3_np(x, y, zc);
                        float dot = dot3_fma(x, kc.x, y, kc.y, zc, kc.z);
                        float d = __fadd_rn(fmaf(-2.0f, dot, uq), kc.w);
                        u32 db = __float_as_uint(d);
                        db = (db & 0x80000000u) ? ~db : (db | 0x80000000u);
                        atomicMin(&cand[rl], ((unsigned long long)db << 32) | (u32)j);
                    }
                    if (a1[r] <= 0.f) {
                        int rl = rloc0 + 32 + (r & 3) + 8 * (r >> 2);
                        const float* up = ub + (size_t)(rowbase + rl) * 3;
                        float x = up[0], y = up[1], zc = up[2];
                        float uq = sq3_np(x, y, zc);
                        float dot = dot3_fma(x, kc.x, y, kc.y, zc, kc.z);
                        float d = __fadd_rn(fmaf(-2.0f, dot, uq), kc.w);
                        u32 db = __float_as_uint(d);
                        db = (db & 0x80000000u) ? ~db : (db | 0x80000000u);
                        atomicMin(&cand[rl], ((unsigned long long)db << 32) | (u32)j);
                    }
                }
            }
        }
        __syncthreads();
        if (c + 1 < NCH_) WRITEV((c + 1) & 1);
        __syncthreads();
    }
    pc[((size_t)(half * B_ + b)) * N_ + rowbase + t] = cand[t];
#undef STAGEV
#undef WRITEV
}

// merge the two j-half packed mins; lower half has smaller j => tie-break ok
__global__ __launch_bounds__(256) void k_nn_merge(
        const unsigned long long* __restrict__ pc, int* __restrict__ idx) {
    int g = blockIdx.x * 256 + threadIdx.x;          // over B*N
    unsigned long long a = pc[g];
    unsigned long long c = pc[(size_t)(B_ * N_) + g];
    idx[g] = (int)(u32)((c < a ? c : a) & 0xFFFFFFFFu);
}

// ------------------------------------------- transpose known_feats -> (b,m,c) bf16
__global__ __launch_bounds__(256) void k_tr_kf(const float* __restrict__ kf,
                                               u16* __restrict__ kfT) {
    __shared__ float lt[64][65];
    const int t = threadIdx.x, b = blockIdx.z;
    const int j0 = blockIdx.x * 64, c0 = blockIdx.y * 64;
    const int jl = t & 63, cl4 = t >> 6;
#pragma unroll
    for (int p = 0; p < 16; ++p) {
        int c = c0 + cl4 + p * 4;
        lt[cl4 + p * 4][jl] = kf[((size_t)(b * C2_ + c)) * M_ + j0 + jl];
    }
    __syncthreads();
    const int cl = t & 63, jr4 = t >> 6;
#pragma unroll
    for (int p = 0; p < 16; ++p) {
        int j = j0 + jr4 + p * 4;
        kfT[((size_t)(b * M_ + j)) * C2_ + c0 + cl] = f2bf(lt[cl][jr4 + p * 4]);
    }
}

// ------------------------------- transpose unknow_feats into newF[...,256:384) bf16
__global__ __launch_bounds__(256) void k_tr_uf(const float* __restrict__ uf,
                                               u16* __restrict__ newF) {
    __shared__ float lt[64][65];
    const int t = threadIdx.x, b = blockIdx.z;
    const int i0 = blockIdx.x * 64, c0 = blockIdx.y * 64;
    const int il = t & 63, cl4 = t >> 6;
#pragma unroll
    for (int p = 0; p < 16; ++p) {
        int c = c0 + cl4 + p * 4;
        lt[cl4 + p * 4][il] = uf[((size_t)(b * C1_ + c)) * N_ + i0 + il];
    }
    __syncthreads();
    const int cl = t & 63, ir4 = t >> 6;
#pragma unroll
    for (int p = 0; p < 16; ++p) {
        int i = i0 + ir4 + p * 4;
        newF[((size_t)(b * N_ + i)) * K1_ + C2_ + c0 + cl] = f2bf(lt[cl][ir4 + p * 4]);
    }
}

// ------------------------------------ gather kfT rows into newF[...,0:256) (dense)
__global__ __launch_bounds__(256) void k_gather(const u16* __restrict__ kfT,
                                                const int* __restrict__ idx,
                                                u16* __restrict__ newF) {
    const int t = threadIdx.x, b = blockIdx.y;
    const int il = t >> 5, qq = t & 31;
    const int i = blockIdx.x * 8 + il;
    const int j = idx[b * N_ + i];
    const uint4* src = (const uint4*)(kfT + ((size_t)(b * M_ + j)) * C2_) + qq;
    uint4* dst = (uint4*)(newF + ((size_t)(b * N_ + i)) * K1_) + qq;
    *dst = *src;
}

// ---------------------------------------------------------------- GEMM1
// y1[b][i][o] (bf16) = newF[b][i][:] . w1[o][:]   tiles 128x128, BK=32
__global__ __launch_bounds__(256) void k_gemm1(const u16* __restrict__ newF,
                                               const float* __restrict__ w1,
                                               u16* __restrict__ y1) {
    __shared__ u16 As[128 * 40];
    __shared__ u16 Bs[128 * 40];
    const int t = threadIdx.x, b = blockIdx.z;
    const int i0 = blockIdx.x * 128, o0 = blockIdx.y * 128;
    const int lane = t & 63, wv = t >> 6, wr = wv >> 1, wc = wv & 1;
    const int col = lane & 15, q = lane >> 4;

    const int rA0 = t >> 2, sA0 = t & 3;   // +256 => row+64, same sub
    const u16* aS0 = newF + ((size_t)(b * N_ + i0 + rA0)) * K1_ + sA0 * 8;
    const u16* aS1 = aS0 + (size_t)64 * K1_;
    const float* bS0 = w1 + (size_t)(o0 + rA0) * K1_ + sA0 * 8;
    const float* bS1 = bS0 + (size_t)64 * K1_;
    u16* aD0 = &As[rA0 * 40 + sA0 * 8];
    u16* aD1 = aD0 + 64 * 40;
    u16* bD0 = &Bs[rA0 * 40 + sA0 * 8];
    u16* bD1 = bD0 + 64 * 40;

    f32x4 acc[4][4];
#pragma unroll
    for (int m = 0; m < 4; ++m)
#pragma unroll
        for (int n = 0; n < 4; ++n) acc[m][n] = (f32x4){0.f, 0.f, 0.f, 0.f};

    uint4 a0 = *(const uint4*)aS0, a1 = *(const uint4*)aS1;
    float4 f00 = *(const float4*)bS0, f01 = *(const float4*)(bS0 + 4);
    float4 f10 = *(const float4*)bS1, f11 = *(const float4*)(bS1 + 4);

    for (int ks = 0; ks < 12; ++ks) {
        __syncthreads();
        *(uint4*)aD0 = a0; *(uint4*)aD1 = a1;
        *(uint4*)bD0 = pack8(f00, f01); *(uint4*)bD1 = pack8(f10, f11);
        __syncthreads();
        if (ks < 11) {
            int ko = (ks + 1) * 32;
            a0 = *(const uint4*)(aS0 + ko); a1 = *(const uint4*)(aS1 + ko);
            f00 = *(const float4*)(bS0 + ko); f01 = *(const float4*)(bS0 + ko + 4);
            f10 = *(const float4*)(bS1 + ko); f11 = *(const float4*)(bS1 + ko + 4);
        }
        const u16* ap = &As[(wr * 64 + col) * 40 + q * 8];
        const u16* bp = &Bs[(wc * 64 + col) * 40 + q * 8];
        bf16x8 af[4], bfr[4];
#pragma unroll
        for (int m = 0; m < 4; ++m) af[m] = *(const bf16x8*)(ap + m * 640);
#pragma unroll
        for (int n = 0; n < 4; ++n) bfr[n] = *(const bf16x8*)(bp + n * 640);
#pragma unroll
        for (int m = 0; m < 4; ++m)
#pragma unroll
            for (int n = 0; n < 4; ++n)
                acc[m][n] = __builtin_amdgcn_mfma_f32_16x16x32_bf16(af[m], bfr[n], acc[m][n], 0, 0, 0);
    }
#pragma unroll
    for (int m = 0; m < 4; ++m)
#pragma unroll
        for (int n = 0; n < 4; ++n) {
            int go = o0 + wc * 64 + n * 16 + col;
#pragma unroll
            for (int r = 0; r < 4; ++r) {
                int gi = i0 + wr * 64 + m * 16 + q * 4 + r;
                y1[((size_t)(b * N_ + gi)) * O1_ + go] = f2bf(acc[m][n][r]);
            }
        }
}

// ------------------------------------------------- BN stats over y1 (bf16, 256 ch)
__global__ __launch_bounds__(256) void k_stats_bf16(const u16* __restrict__ y1,
                                                    float* __restrict__ sum,
                                                    float* __restrict__ sq) {
    const int t = threadIdx.x;
    const int row0 = blockIdx.x * 1024;
    float s = 0.f, qq = 0.f;
    for (int r = 0; r < 1024; ++r) {
        float v = bf2f(y1[((size_t)(row0 + r)) * O1_ + t]);
        s += v; qq = fmaf(v, v, qq);
    }
    atomicAdd(&sum[t], s);
    atomicAdd(&sq[t], qq);
}

// ------------------------------------------------- BN stats over y2 (f32, 128 ch)
__global__ __launch_bounds__(256) void k_stats_f32(const float* __restrict__ y2,
                                                   float* __restrict__ sum,
                                                   float* __restrict__ sq) {
    const int t = threadIdx.x;
    const int o = t & 127, h = t >> 7;
    const int row0 = blockIdx.x * 1024;
    float s = 0.f, qq = 0.f;
    for (int r = 0; r < 512; ++r) {
        float v = y2[((size_t)(row0 + r * 2 + h)) * O2_ + o];
        s += v; qq = fmaf(v, v, qq);
    }
    atomicAdd(&sum[o], s);
    atomicAdd(&sq[o], qq);
}

__global__ void k_bn_fin(const float* __restrict__ sum, const float* __restrict__ sq,
                         const float* __restrict__ gamma, const float* __restrict__ beta,
                         float* __restrict__ scale, float* __restrict__ bias,
                         int C, float invN) {
    int t = threadIdx.x;
    if (t < C) {
        float mean = sum[t] * invN;
        float var = sq[t] * invN - mean * mean;
        float rs = rsqrtf(var + 1e-5f);
        float sc = gamma[t] * rs;
        scale[t] = sc;
        bias[t] = beta[t] - mean * sc;
    }
}

// ---------------------------------------------------------------- GEMM2
// y2[b][i][o] (f32) = relu(bn1(y1))[b][i][:] . w2[o][:]  (BN1 fused in A-staging)
__global__ __launch_bounds__(256) void k_gemm2(const u16* __restrict__ y1,
                                               const float* __restrict__ w2,
                                               const float* __restrict__ s1,
                                               const float* __restrict__ b1,
                                               float* __restrict__ y2) {
    __shared__ u16 As[128 * 40];
    __shared__ u16 Bs[128 * 40];
    const int t = threadIdx.x, b = blockIdx.z;
    const int i0 = blockIdx.x * 128;
    const int lane = t & 63, wv = t >> 6, wr = wv >> 1, wc = wv & 1;
    const int col = lane & 15, q = lane >> 4;

    const int rA0 = t >> 2, sA0 = t & 3;
    const u16* aS0 = y1 + ((size_t)(b * N_ + i0 + rA0)) * O1_ + sA0 * 8;
    const u16* aS1 = aS0 + (size_t)64 * O1_;
    const float* bS0 = w2 + (size_t)rA0 * O1_ + sA0 * 8;
    const float* bS1 = bS0 + (size_t)64 * O1_;
    u16* aD0 = &As[rA0 * 40 + sA0 * 8];
    u16* aD1 = aD0 + 64 * 40;
    u16* bD0 = &Bs[rA0 * 40 + sA0 * 8];
    u16* bD1 = bD0 + 64 * 40;

    f32x4 acc[4][4];
#pragma unroll
    for (int m = 0; m < 4; ++m)
#pragma unroll
        for (int n = 0; n < 4; ++n) acc[m][n] = (f32x4){0.f, 0.f, 0.f, 0.f};

    uint4 a0 = *(const uint4*)aS0, a1 = *(const uint4*)aS1;
    float4 f00 = *(const float4*)bS0, f01 = *(const float4*)(bS0 + 4);
    float4 f10 = *(const float4*)bS1, f11 = *(const float4*)(bS1 + 4);

    for (int ks = 0; ks < 8; ++ks) {
        int oc = ks * 32 + sA0 * 8;
        float4 sc0 = *(const float4*)(s1 + oc), sc1 = *(const float4*)(s1 + oc + 4);
        float4 bb0 = *(const float4*)(b1 + oc), bb1 = *(const float4*)(b1 + oc + 4);
        uint4 h0, h1;
        {
            const u16* hs = (const u16*)&a0;
            float v[8];
            v[0] = fmaxf(fmaf(bf2f(hs[0]), sc0.x, bb0.x), 0.f);
            v[1] = fmaxf(fmaf(bf2f(hs[1]), sc0.y, bb0.y), 0.f);
            v[2] = fmaxf(fmaf(bf2f(hs[2]), sc0.z, bb0.z), 0.f);
            v[3] = fmaxf(fmaf(bf2f(hs[3]), sc0.w, bb0.w), 0.f);
            v[4] = fmaxf(fmaf(bf2f(hs[4]), sc1.x, bb1.x), 0.f);
            v[5] = fmaxf(fmaf(bf2f(hs[5]), sc1.y, bb1.y), 0.f);
            v[6] = fmaxf(fmaf(bf2f(hs[6]), sc1.z, bb1.z), 0.f);
            v[7] = fmaxf(fmaf(bf2f(hs[7]), sc1.w, bb1.w), 0.f);
            h0.x = pack2(v[0], v[1]); h0.y = pack2(v[2], v[3]);
            h0.z = pack2(v[4], v[5]); h0.w = pack2(v[6], v[7]);
        }
        {
            const u16* hs = (const u16*)&a1;
            float v[8];
            v[0] = fmaxf(fmaf(bf2f(hs[0]), sc0.x, bb0.x), 0.f);
            v[1] = fmaxf(fmaf(bf2f(hs[1]), sc0.y, bb0.y), 0.f);
            v[2] = fmaxf(fmaf(bf2f(hs[2]), sc0.z, bb0.z), 0.f);
            v[3] = fmaxf(fmaf(bf2f(hs[3]), sc0.w, bb0.w), 0.f);
            v[4] = fmaxf(fmaf(bf2f(hs[4]), sc1.x, bb1.x), 0.f);
            v[5] = fmaxf(fmaf(bf2f(hs[5]), sc1.y, bb1.y), 0.f);
            v[6] = fmaxf(fmaf(bf2f(hs[6]), sc1.z, bb1.z), 0.f);
            v[7] = fmaxf(fmaf(bf2f(hs[7]), sc1.w, bb1.w), 0.f);
            h1.x = pack2(v[0], v[1]); h1.y = pack2(v[2], v[3]);
            h1.z = pack2(v[4], v[5]); h1.w = pack2(v[6], v[7]);
        }
        __syncthreads();
        *(uint4*)aD0 = h0; *(uint4*)aD1 = h1;
        *(uint4*)bD0 = pack8(f00, f01); *(uint4*)bD1 = pack8(f10, f11);
        __syncthreads();
        if (ks < 7) {
            int ko = (ks + 1) * 32;
            a0 = *(const uint4*)(aS0 + ko); a1 = *(const uint4*)(aS1 + ko);
            f00 = *(const float4*)(bS0 + ko); f01 = *(const float4*)(bS0 + ko + 4);
            f10 = *(const float4*)(bS1 + ko); f11 = *(const float4*)(bS1 + ko + 4);
        }
        const u16* ap = &As[(wr * 64 + col) * 40 + q * 8];
        const u16* bp = &Bs[(wc * 64 + col) * 40 + q * 8];
        bf16x8 af[4], bfr[4];
#pragma unroll
        for (int m = 0; m < 4; ++m) af[m] = *(const bf16x8*)(ap + m * 640);
#pragma unroll
        for (int n = 0; n < 4; ++n) bfr[n] = *(const bf16x8*)(bp + n * 640);
#pragma unroll
        for (int m = 0; m < 4; ++m)
#pragma unroll
            for (int n = 0; n < 4; ++n)
                acc[m][n] = __builtin_amdgcn_mfma_f32_16x16x32_bf16(af[m], bfr[n], acc[m][n], 0, 0, 0);
    }
#pragma unroll
    for (int m = 0; m < 4; ++m)
#pragma unroll
        for (int n = 0; n < 4; ++n) {
            int go = wc * 64 + n * 16 + col;
#pragma unroll
            for (int r = 0; r < 4; ++r) {
                int gi = i0 + wr * 64 + m * 16 + q * 4 + r;
                y2[((size_t)(b * N_ + gi)) * O2_ + go] = acc[m][n][r];
            }
        }
}

// ---------------------------- BN2 affine + ReLU + transpose (b,i,o)->(b,o,i) out
__global__ __launch_bounds__(256) void k_out(const float* __restrict__ y2,
                                             const float* __restrict__ s2,
                                             const float* __restrict__ b2,
                                             float* __restrict__ out) {
    __shared__ float lt[64 * 65];
    const int t = threadIdx.x, b = blockIdx.z;
    const int i0 = blockIdx.x * 64, o0 = blockIdx.y * 64;
    const int oc = t & 63, ir4 = t >> 6;
    const float sc = s2[o0 + oc], bs = b2[o0 + oc];
#pragma unroll
    for (int p = 0; p < 16; ++p) {
        int i = i0 + ir4 + p * 4;
        float v = y2[((size_t)(b * N_ + i)) * O2_ + o0 + oc];
        lt[oc * 65 + ir4 + p * 4] = fmaxf(fmaf(v, sc, bs), 0.f);
    }
    __syncthreads();
    const int il = t & 63, or4 = t >> 6;
#pragma unroll
    for (int p = 0; p < 16; ++p) {
        int o = o0 + or4 + p * 4;
        out[((size_t)(b * O2_ + o)) * N_ + i0 + il] = lt[(or4 + p * 4) * 65 + il];
    }
}

extern "C" void kernel_launch(void* const* d_in, const int* in_sizes, int n_in,
                              void* d_out, int out_size, void* d_ws, size_t ws_size,
                              hipStream_t stream) {
    const float* unknown = (const float*)d_in[0];
    const float* known   = (const float*)d_in[1];
    const float* uf      = (const float*)d_in[2];
    const float* kf      = (const float*)d_in[3];
    const float* w1      = (const float*)d_in[4];
    const float* g1      = (const float*)d_in[5];
    const float* be1     = (const float*)d_in[6];
    const float* w2      = (const float*)d_in[7];
    const float* g2      = (const float*)d_in[8];
    const float* be2     = (const float*)d_in[9];
    float* out = (float*)d_out;

    char* w = (char*)d_ws;
    // stats block (zeroed each call): bn1_sum[256] bn1_sq[256] bn2_sum[128] bn2_sq[128]
    float* bn1_sum = (float*)w;
    float* bn1_sq  = bn1_sum + 256;
    float* bn2_sum = bn1_sq + 256;
    float* bn2_sq  = bn2_sum + 128;
    float* s1 = (float*)(w + 4096);     // 256
    float* b1 = s1 + 256;               // 256
    float* s2 = b1 + 256;               // 128
    float* b2 = s2 + 128;               // 128
    int* idx = (int*)(w + 8192);                        // 512 KiB
    u16* newF = (u16*)(w + 532480);                     // (B,n,384) bf16 = 100.7 MB
    float* y2 = (float*)(w + 532480);                   // alias (newF dead by GEMM2)
    size_t R2 = 532480 + 100663296ULL;
    // NN scratch (dead before y1 is written):
    u16*   Aprep = (u16*)(w + R2);                      // 4 MiB (4096 tiles * 1KB)
    u16*   Bprep = (u16*)(w + R2 + 4194304ULL);         // 1 MiB (1024 tiles * 1KB)
    float4* kco  = (float4*)(w + R2 + 5242880ULL);      // 512 KiB
    unsigned long long* pc = (unsigned long long*)(w + R2 + 5767168ULL); // 2 MiB
    u16*  kfT = (u16*)(w + R2 + 16777216ULL);           // 16.7MB (dead before y1)
    u16*   y1 = (u16*)(w + R2);                         // (B,n,256) bf16 = 67 MB

    hipMemsetAsync(w, 0, 3072, stream);   // zero BN accumulators

    k_prep_u<<<512, 256, 0, stream>>>(unknown, Aprep);
    k_prep_k<<<128, 256, 0, stream>>>(known, Bprep, kco);
    k_nn<<<dim3(N_ / 256, 2, B_), 256, 0, stream>>>(Aprep, Bprep, unknown, kco, pc);
    k_nn_merge<<<512, 256, 0, stream>>>(pc, idx);
    k_tr_kf<<<dim3(256, 4, 2), 256, 0, stream>>>(kf, kfT);
    k_tr_uf<<<dim3(1024, 2, 2), 256, 0, stream>>>(uf, newF);
    k_gather<<<dim3(8192, 2), 256, 0, stream>>>(kfT, idx, newF);
    k_gemm1<<<dim3(512, 2, 2), 256, 0, stream>>>(newF, w1, y1);
    k_stats_bf16<<<128, 256, 0, stream>>>(y1, bn1_sum, bn1_sq);
    k_bn_fin<<<1, 256, 0, stream>>>(bn1_sum, bn1_sq, g1, be1, s1, b1, 256, 1.f / 131072.f);
    k_gemm2<<<dim3(512, 1, 2), 256, 0, stream>>>(y1, w2, s1, b1, y2);
    k_stats_f32<<<128, 256, 0, stream>>>(y2, bn2_sum, bn2_sq);
    k_bn_fin<<<1, 256, 0, stream>>>(bn2_sum, bn2_sq, g2, be2, s2, b2, 128, 1.f / 131072.f);
    k_out<<<dim3(1024, 2, 2), 256, 0, stream>>>(y2, s2, b2, out);
}

// Round 4
// 593.951 us; speedup vs baseline: 1.5208x; 1.0414x over previous
//
#include <hip/hip_runtime.h>

typedef unsigned short u16;
typedef unsigned int u32;
typedef __bf16 bf16x8 __attribute__((ext_vector_type(8)));
typedef _Float16 f16;
typedef _Float16 f16x8 __attribute__((ext_vector_type(8)));
typedef float f32x4 __attribute__((ext_vector_type(4)));
typedef float f32x16 __attribute__((ext_vector_type(16)));

#define B_ 2
#define N_ 65536
#define M_ 16384
#define C1_ 128
#define C2_ 256
#define K1_ 384   // C1+C2
#define O1_ 256   // mlp[1]
#define O2_ 128   // mlp[2]
#define JT_ 512       // 32-wide j-tiles per batch (M_/32)
#define CH_ 16        // j-tiles per LDS chunk (16 KB)
#define NCH_ ((JT_/2)/CH_)   // chunks per j-half = 16
#define EPS2_ 6.0e-3f // 2*eps certified ordering slack (verified rounds 1-3)
#define TFIN_ 1.25e-4f // threshold-fold inflation >= worst-case f16 hi/lo fold error

__device__ __forceinline__ u16 f2bf(float f) {
    u32 u = __float_as_uint(f);
    u32 r = (u + 0x7FFFu + ((u >> 16) & 1u)) >> 16;   // RNE
    return (u16)r;
}
__device__ __forceinline__ float bf2f(u16 h) {
    return __uint_as_float(((u32)h) << 16);
}
__device__ __forceinline__ u32 pack2(float lo, float hi) {
    return (u32)f2bf(lo) | ((u32)f2bf(hi) << 16);
}
__device__ __forceinline__ uint4 pack8(float4 a, float4 b) {
    uint4 r;
    r.x = pack2(a.x, a.y); r.y = pack2(a.z, a.w);
    r.z = pack2(b.x, b.y); r.w = pack2(b.z, b.w);
    return r;
}
__device__ __forceinline__ u16 h2u(f16 h) {
    union { f16 h; u16 u; } c; c.h = h; return c.u;
}

// Exact-IEEE fp32 mul with an optimization barrier so the backend can NEVER
// contract it into an FMA (HIP default is -ffp-contract=fast).
__device__ __forceinline__ float mul_rn(float a, float b) {
    float p = __fmul_rn(a, b);
    asm volatile("" : "+v"(p));
    return p;
}
// u2/k2: elementwise-square (each product rounded) + ascending reduce
__device__ __forceinline__ float sq3_np(float x, float y, float z) {
    return __fadd_rn(__fadd_rn(mul_rn(x, x), mul_rn(y, y)), mul_rn(z, z));
}
// Eigen/XLA gebp K=3 dot: ascending k, FMA accumulate into rounded first product
__device__ __forceinline__ float dot3_fma(float a0, float b0, float a1, float b1,
                                          float a2, float b2) {
    return fmaf(a2, b2, fmaf(a1, b1, mul_rn(a0, b0)));
}

// ============================== NN search: 32x32x16 MFMA filter + exact refine
// Numerics identical to the round-3 kernel (passed, bit-exact indices):
// key val_ij = k2_j - 2*dot_ij via mfma_f32_32x32x16_f16; K-slots 0-8 split
// coords (A has -2 folded), 9-10 k2 hi/lo (A=1.0), 11-12 pass-B threshold fold
// (A=-(thr+TFIN_) hi/lo, B=1.0) => MFMA emits val - thr'; thr' >= thr =>
// candidate superset => exact refine reproduces the reference argmin exactly.
// Restructure vs r3 (anti-spill): ONE 32-row tile per wave (was two), 128 rows
// per block, grid x2. Peak live state: af(4) + rm(16) + a,ca(32) + vs(16) +
// bf(8) + addr ~= 100 VGPR -> fits 4 waves/SIMD without the (256,4) cap that
// forced 94 MB of scratch spill traffic in r3. launch_bounds(256,3) only caps
// the allocator at 170; actual (<128) still gives 4 blocks/CU (LDS 33.6 KB).

__global__ __launch_bounds__(256) void k_prep_u(const float* __restrict__ unk,
                                                u16* __restrict__ Aprep) {
    int g = blockIdx.x * 256 + threadIdx.x;          // over B*N
    const float* up = unk + (size_t)g * 3;
    float tx = -2.f * up[0], ty = -2.f * up[1], tz = -2.f * up[2];
    f16 xh = (f16)tx; f16 xl = (f16)(tx - (float)xh);
    f16 yh = (f16)ty; f16 yl = (f16)(ty - (float)yh);
    f16 zh = (f16)tz; f16 zl = (f16)(tz - (float)zh);
    u16 lo[8] = {h2u(xh), h2u(xh), h2u(xl), h2u(yh), h2u(yh), h2u(yl), h2u(zh), h2u(zh)};
    u16 hi[8] = {h2u(zl), 0x3C00u, 0x3C00u, 0, 0, 0, 0, 0};
    u16* tb = Aprep + ((size_t)(g >> 5)) * 512;      // tile = 64 lanes * 8 u16
    int r = g & 31;
    *(uint4*)(tb + r * 8) = *(uint4*)lo;
    *(uint4*)(tb + (r + 32) * 8) = *(uint4*)hi;
}

__global__ __launch_bounds__(256) void k_prep_k(const float* __restrict__ kn,
                                                u16* __restrict__ Bprep,
                                                float4* __restrict__ kco) {
    int g = blockIdx.x * 256 + threadIdx.x;          // over B*M
    const float* kp = kn + (size_t)g * 3;
    float x = kp[0], y = kp[1], z = kp[2];
    float qv = sq3_np(x, y, z);                       // EXACT ref k2 sequence
    f16 xh = (f16)x; f16 xl = (f16)(x - (float)xh);
    f16 yh = (f16)y; f16 yl = (f16)(y - (float)yh);
    f16 zh = (f16)z; f16 zl = (f16)(z - (float)zh);
    f16 qh = (f16)qv; f16 ql = (f16)(qv - (float)qh);
    u16 lo[8] = {h2u(xh), h2u(xl), h2u(xh), h2u(yh), h2u(yl), h2u(yh), h2u(zh), h2u(zl)};
    // slots 11,12 = 1.0 so pass B's A-side -thr hi/lo ride the same MFMA
    u16 hi[8] = {h2u(zh), h2u(qh), h2u(ql), 0x3C00u, 0x3C00u, 0, 0, 0};
    u16* tb = Bprep + ((size_t)(g >> 5)) * 512;
    int r = g & 31;
    *(uint4*)(tb + r * 8) = *(uint4*)lo;
    *(uint4*)(tb + (r + 32) * 8) = *(uint4*)hi;
    kco[g] = make_float4(x, y, z, qv);
}

__global__ __launch_bounds__(256, 3) void k_nn(
        const u16* __restrict__ Aprep, const u16* __restrict__ Bprep,
        const float* __restrict__ unk, const float4* __restrict__ kco,
        unsigned long long* __restrict__ pc) {
    __shared__ u16 sB[2][CH_ * 512];                 // 2 x 16 KB
    __shared__ unsigned long long cand[128];
    __shared__ float thrS[128];
    const int t = threadIdx.x;
    const int half = blockIdx.y, b = blockIdx.z;
    const int lane = t & 63, w = t >> 6;
    const int rowbase = blockIdx.x * 128;            // 128 rows per block
    // wave w owns ONE 32-row tile: rows [rowbase + w*32, +32)
    const u16* at = Aprep + (((size_t)(b * N_ + rowbase + w * 32)) >> 5) * 512;
    f16x8 af = *(const f16x8*)(at + lane * 8);
    const u16* Bsrc = Bprep + ((size_t)b * JT_ + (size_t)half * (JT_ / 2)) * 512;
    if (t < 128) cand[t] = ~0ULL;

    uint4 vs0, vs1, vs2, vs3;
#define STAGEV(c) { const u16* sp = Bsrc + (size_t)(c) * (CH_ * 512) + t * 8;  \
    vs0 = *(const uint4*)sp;          vs1 = *(const uint4*)(sp + 2048);        \
    vs2 = *(const uint4*)(sp + 4096); vs3 = *(const uint4*)(sp + 6144); }
#define WRITEV(bi) { u16* dp = &sB[bi][t * 8];                                 \
    *(uint4*)dp = vs0;          *(uint4*)(dp + 2048) = vs1;                    \
    *(uint4*)(dp + 4096) = vs2; *(uint4*)(dp + 6144) = vs3; }

    const f32x16 zz = {0.f,0.f,0.f,0.f,0.f,0.f,0.f,0.f,0.f,0.f,0.f,0.f,0.f,0.f,0.f,0.f};

    // ---------------- pass A: rowmin over this j-half ----------------
    f32x16 rm;
#pragma unroll
    for (int r = 0; r < 16; ++r) rm[r] = 3.4e38f;

    STAGEV(0); WRITEV(0);
    __syncthreads();
    for (int c = 0; c < NCH_; ++c) {
        if (c + 1 < NCH_) STAGEV(c + 1);
        const u16* bb = sB[c & 1];
#pragma unroll 2
        for (int tp = 0; tp < CH_; tp += 2) {       // paired j-tiles -> v_min3
            f16x8 bf0 = *(const f16x8*)(bb + tp * 512 + lane * 8);
            f16x8 bf1 = *(const f16x8*)(bb + tp * 512 + 512 + lane * 8);
            f32x16 a  = __builtin_amdgcn_mfma_f32_32x32x16_f16(af, bf0, zz, 0, 0, 0);
            f32x16 ca = __builtin_amdgcn_mfma_f32_32x32x16_f16(af, bf1, zz, 0, 0, 0);
#pragma unroll
            for (int r = 0; r < 16; ++r)
                rm[r] = fminf(fminf(rm[r], a[r]), ca[r]);
        }
        __syncthreads();
        if (c + 1 < NCH_) WRITEV((c + 1) & 1);
        __syncthreads();
    }

    STAGEV(0);   // prefetch pass-B chunk 0; latency hides under reduce

    // reduce over the 32 cols -> per-row thresholds into LDS (wave-local rows)
#pragma unroll
    for (int r = 0; r < 16; ++r) {
        float v = rm[r];
        v = fminf(v, __shfl_xor(v, 1));
        v = fminf(v, __shfl_xor(v, 2));
        v = fminf(v, __shfl_xor(v, 4));
        v = fminf(v, __shfl_xor(v, 8));
        v = fminf(v, __shfl_xor(v, 16));
        if ((lane & 31) == 0) {
            int rl = w * 32 + ((lane >> 5) << 2) + (r & 3) + 8 * (r >> 2);
            thrS[rl] = v + EPS2_;
        }
    }
    __syncthreads();
    // patch A fragment: k-slots 11,12 (lanes>=32, elems 3,4) = -(thr+TFIN_) hi/lo
    if (lane >= 32) {
        float tf = thrS[w * 32 + (lane & 31)] + TFIN_;
        f16 h0 = (f16)(-tf);
        af[3] = h0; af[4] = (f16)(-tf - (float)h0);
    }
    WRITEV(0);
    __syncthreads();

    // ---------------- pass B: exact refine (MFMA emits val - thr') ----------
    const float4* kcb = kco + (size_t)b * M_;
    const float* ub = unk + (size_t)b * N_ * 3;
    const int rloc0 = w * 32 + ((lane >> 5) << 2);   // + (r&3)+8*(r>>2)
    const int jb0 = half * (M_ / 2);

    for (int c = 0; c < NCH_; ++c) {
        if (c + 1 < NCH_) STAGEV(c + 1);
        const u16* bb = sB[c & 1];
#pragma unroll 2
        for (int tt = 0; tt < CH_; ++tt) {
            f16x8 bf = *(const f16x8*)(bb + tt * 512 + lane * 8);
            f32x16 a0 = __builtin_amdgcn_mfma_f32_32x32x16_f16(af, bf, zz, 0, 0, 0);
            // sign test via min3 tree: a<=0 iff candidate (thr folded into MFMA)
            float u0 = fminf(fminf(a0[0], a0[1]), a0[2]);
            float u1 = fminf(fminf(a0[3], a0[4]), a0[5]);
            float u2 = fminf(fminf(a0[6], a0[7]), a0[8]);
            float u3 = fminf(fminf(a0[9], a0[10]), a0[11]);
            float u4 = fminf(fminf(a0[12], a0[13]), a0[14]);
            float tm0 = fminf(fminf(fminf(u0, u1), a0[15]), fminf(fminf(u2, u3), u4));
            unsigned long long m = __ballot(tm0 <= 0.f);
            if (m) {                                 // wave-uniform, rarely taken
                int j = jb0 + (c * CH_ + tt) * 32 + (lane & 31);
                float4 kc = kcb[j];
#pragma unroll
                for (int r = 0; r < 16; ++r) {
                    if (a0[r] <= 0.f) {
                        int rl = rloc0 + (r & 3) + 8 * (r >> 2);
                        const float* up = ub + (size_t)(rowbase + rl) * 3;
                        float x = up[0], y = up[1], zc = up[2];
                        float uq = sq3_np(x, y, zc);
                        float dot = dot3_fma(x, kc.x, y, kc.y, zc, kc.z);
                        float d = __fadd_rn(fmaf(-2.0f, dot, uq), kc.w);
                        u32 db = __float_as_uint(d);
                        db = (db & 0x80000000u) ? ~db : (db | 0x80000000u);
                        atomicMin(&cand[rl], ((unsigned long long)db << 32) | (u32)j);
                    }
                }
            }
        }
        __syncthreads();
        if (c + 1 < NCH_) WRITEV((c + 1) & 1);
        __syncthreads();
    }
    if (t < 128)
        pc[((size_t)(half * B_ + b)) * N_ + rowbase + t] = cand[t];
#undef STAGEV
#undef WRITEV
}

// merge the two j-half packed mins; lower half has smaller j => tie-break ok
__global__ __launch_bounds__(256) void k_nn_merge(
        const unsigned long long* __restrict__ pc, int* __restrict__ idx) {
    int g = blockIdx.x * 256 + threadIdx.x;          // over B*N
    unsigned long long a = pc[g];
    unsigned long long c = pc[(size_t)(B_ * N_) + g];
    idx[g] = (int)(u32)((c < a ? c : a) & 0xFFFFFFFFu);
}

// ------------------------------------------- transpose known_feats -> (b,m,c) bf16
__global__ __launch_bounds__(256) void k_tr_kf(const float* __restrict__ kf,
                                               u16* __restrict__ kfT) {
    __shared__ float lt[64][65];
    const int t = threadIdx.x, b = blockIdx.z;
    const int j0 = blockIdx.x * 64, c0 = blockIdx.y * 64;
    const int jl = t & 63, cl4 = t >> 6;
#pragma unroll
    for (int p = 0; p < 16; ++p) {
        int c = c0 + cl4 + p * 4;
        lt[cl4 + p * 4][jl] = kf[((size_t)(b * C2_ + c)) * M_ + j0 + jl];
    }
    __syncthreads();
    const int cl = t & 63, jr4 = t >> 6;
#pragma unroll
    for (int p = 0; p < 16; ++p) {
        int j = j0 + jr4 + p * 4;
        kfT[((size_t)(b * M_ + j)) * C2_ + c0 + cl] = f2bf(lt[cl][jr4 + p * 4]);
    }
}

// ------------------------------- transpose unknow_feats into newF[...,256:384) bf16
__global__ __launch_bounds__(256) void k_tr_uf(const float* __restrict__ uf,
                                               u16* __restrict__ newF) {
    __shared__ float lt[64][65];
    const int t = threadIdx.x, b = blockIdx.z;
    const int i0 = blockIdx.x * 64, c0 = blockIdx.y * 64;
    const int il = t & 63, cl4 = t >> 6;
#pragma unroll
    for (int p = 0; p < 16; ++p) {
        int c = c0 + cl4 + p * 4;
        lt[cl4 + p * 4][il] = uf[((size_t)(b * C1_ + c)) * N_ + i0 + il];
    }
    __syncthreads();
    const int cl = t & 63, ir4 = t >> 6;
#pragma unroll
    for (int p = 0; p < 16; ++p) {
        int i = i0 + ir4 + p * 4;
        newF[((size_t)(b * N_ + i)) * K1_ + C2_ + c0 + cl] = f2bf(lt[cl][ir4 + p * 4]);
    }
}

// ------------------------------------ gather kfT rows into newF[...,0:256) (dense)
__global__ __launch_bounds__(256) void k_gather(const u16* __restrict__ kfT,
                                                const int* __restrict__ idx,
                                                u16* __restrict__ newF) {
    const int t = threadIdx.x, b = blockIdx.y;
    const int il = t >> 5, qq = t & 31;
    const int i = blockIdx.x * 8 + il;
    const int j = idx[b * N_ + i];
    const uint4* src = (const uint4*)(kfT + ((size_t)(b * M_ + j)) * C2_) + qq;
    uint4* dst = (uint4*)(newF + ((size_t)(b * N_ + i)) * K1_) + qq;
    *dst = *src;
}

// ---------------------------------------------------------------- GEMM1
// y1[b][i][o] (bf16) = newF[b][i][:] . w1[o][:]   tiles 128x128, BK=32
__global__ __launch_bounds__(256) void k_gemm1(const u16* __restrict__ newF,
                                               const float* __restrict__ w1,
                                               u16* __restrict__ y1) {
    __shared__ u16 As[128 * 40];
    __shared__ u16 Bs[128 * 40];
    const int t = threadIdx.x, b = blockIdx.z;
    const int i0 = blockIdx.x * 128, o0 = blockIdx.y * 128;
    const int lane = t & 63, wv = t >> 6, wr = wv >> 1, wc = wv & 1;
    const int col = lane & 15, q = lane >> 4;

    const int rA0 = t >> 2, sA0 = t & 3;   // +256 => row+64, same sub
    const u16* aS0 = newF + ((size_t)(b * N_ + i0 + rA0)) * K1_ + sA0 * 8;
    const u16* aS1 = aS0 + (size_t)64 * K1_;
    const float* bS0 = w1 + (size_t)(o0 + rA0) * K1_ + sA0 * 8;
    const float* bS1 = bS0 + (size_t)64 * K1_;
    u16* aD0 = &As[rA0 * 40 + sA0 * 8];
    u16* aD1 = aD0 + 64 * 40;
    u16* bD0 = &Bs[rA0 * 40 + sA0 * 8];
    u16* bD1 = bD0 + 64 * 40;

    f32x4 acc[4][4];
#pragma unroll
    for (int m = 0; m < 4; ++m)
#pragma unroll
        for (int n = 0; n < 4; ++n) acc[m][n] = (f32x4){0.f, 0.f, 0.f, 0.f};

    uint4 a0 = *(const uint4*)aS0, a1 = *(const uint4*)aS1;
    float4 f00 = *(const float4*)bS0, f01 = *(const float4*)(bS0 + 4);
    float4 f10 = *(const float4*)bS1, f11 = *(const float4*)(bS1 + 4);

    for (int ks = 0; ks < 12; ++ks) {
        __syncthreads();
        *(uint4*)aD0 = a0; *(uint4*)aD1 = a1;
        *(uint4*)bD0 = pack8(f00, f01); *(uint4*)bD1 = pack8(f10, f11);
        __syncthreads();
        if (ks < 11) {
            int ko = (ks + 1) * 32;
            a0 = *(const uint4*)(aS0 + ko); a1 = *(const uint4*)(aS1 + ko);
            f00 = *(const float4*)(bS0 + ko); f01 = *(const float4*)(bS0 + ko + 4);
            f10 = *(const float4*)(bS1 + ko); f11 = *(const float4*)(bS1 + ko + 4);
        }
        const u16* ap = &As[(wr * 64 + col) * 40 + q * 8];
        const u16* bp = &Bs[(wc * 64 + col) * 40 + q * 8];
        bf16x8 af[4], bfr[4];
#pragma unroll
        for (int m = 0; m < 4; ++m) af[m] = *(const bf16x8*)(ap + m * 640);
#pragma unroll
        for (int n = 0; n < 4; ++n) bfr[n] = *(const bf16x8*)(bp + n * 640);
#pragma unroll
        for (int m = 0; m < 4; ++m)
#pragma unroll
            for (int n = 0; n < 4; ++n)
                acc[m][n] = __builtin_amdgcn_mfma_f32_16x16x32_bf16(af[m], bfr[n], acc[m][n], 0, 0, 0);
    }
#pragma unroll
    for (int m = 0; m < 4; ++m)
#pragma unroll
        for (int n = 0; n < 4; ++n) {
            int go = o0 + wc * 64 + n * 16 + col;
#pragma unroll
            for (int r = 0; r < 4; ++r) {
                int gi = i0 + wr * 64 + m * 16 + q * 4 + r;
                y1[((size_t)(b * N_ + gi)) * O1_ + go] = f2bf(acc[m][n][r]);
            }
        }
}

// ------------------------------------------------- BN stats over y1 (bf16, 256 ch)
__global__ __launch_bounds__(256) void k_stats_bf16(const u16* __restrict__ y1,
                                                    float* __restrict__ sum,
                                                    float* __restrict__ sq) {
    const int t = threadIdx.x;
    const int row0 = blockIdx.x * 1024;
    float s = 0.f, qq = 0.f;
    for (int r = 0; r < 1024; ++r) {
        float v = bf2f(y1[((size_t)(row0 + r)) * O1_ + t]);
        s += v; qq = fmaf(v, v, qq);
    }
    atomicAdd(&sum[t], s);
    atomicAdd(&sq[t], qq);
}

// ------------------------------------------------- BN stats over y2 (f32, 128 ch)
__global__ __launch_bounds__(256) void k_stats_f32(const float* __restrict__ y2,
                                                   float* __restrict__ sum,
                                                   float* __restrict__ sq) {
    const int t = threadIdx.x;
    const int o = t & 127, h = t >> 7;
    const int row0 = blockIdx.x * 1024;
    float s = 0.f, qq = 0.f;
    for (int r = 0; r < 512; ++r) {
        float v = y2[((size_t)(row0 + r * 2 + h)) * O2_ + o];
        s += v; qq = fmaf(v, v, qq);
    }
    atomicAdd(&sum[o], s);
    atomicAdd(&sq[o], qq);
}

__global__ void k_bn_fin(const float* __restrict__ sum, const float* __restrict__ sq,
                         const float* __restrict__ gamma, const float* __restrict__ beta,
                         float* __restrict__ scale, float* __restrict__ bias,
                         int C, float invN) {
    int t = threadIdx.x;
    if (t < C) {
        float mean = sum[t] * invN;
        float var = sq[t] * invN - mean * mean;
        float rs = rsqrtf(var + 1e-5f);
        float sc = gamma[t] * rs;
        scale[t] = sc;
        bias[t] = beta[t] - mean * sc;
    }
}

// ---------------------------------------------------------------- GEMM2
// y2[b][i][o] (f32) = relu(bn1(y1))[b][i][:] . w2[o][:]  (BN1 fused in A-staging)
__global__ __launch_bounds__(256) void k_gemm2(const u16* __restrict__ y1,
                                               const float* __restrict__ w2,
                                               const float* __restrict__ s1,
                                               const float* __restrict__ b1,
                                               float* __restrict__ y2) {
    __shared__ u16 As[128 * 40];
    __shared__ u16 Bs[128 * 40];
    const int t = threadIdx.x, b = blockIdx.z;
    const int i0 = blockIdx.x * 128;
    const int lane = t & 63, wv = t >> 6, wr = wv >> 1, wc = wv & 1;
    const int col = lane & 15, q = lane >> 4;

    const int rA0 = t >> 2, sA0 = t & 3;
    const u16* aS0 = y1 + ((size_t)(b * N_ + i0 + rA0)) * O1_ + sA0 * 8;
    const u16* aS1 = aS0 + (size_t)64 * O1_;
    const float* bS0 = w2 + (size_t)rA0 * O1_ + sA0 * 8;
    const float* bS1 = bS0 + (size_t)64 * O1_;
    u16* aD0 = &As[rA0 * 40 + sA0 * 8];
    u16* aD1 = aD0 + 64 * 40;
    u16* bD0 = &Bs[rA0 * 40 + sA0 * 8];
    u16* bD1 = bD0 + 64 * 40;

    f32x4 acc[4][4];
#pragma unroll
    for (int m = 0; m < 4; ++m)
#pragma unroll
        for (int n = 0; n < 4; ++n) acc[m][n] = (f32x4){0.f, 0.f, 0.f, 0.f};

    uint4 a0 = *(const uint4*)aS0, a1 = *(const uint4*)aS1;
    float4 f00 = *(const float4*)bS0, f01 = *(const float4*)(bS0 + 4);
    float4 f10 = *(const float4*)bS1, f11 = *(const float4*)(bS1 + 4);

    for (int ks = 0; ks < 8; ++ks) {
        int oc = ks * 32 + sA0 * 8;
        float4 sc0 = *(const float4*)(s1 + oc), sc1 = *(const float4*)(s1 + oc + 4);
        float4 bb0 = *(const float4*)(b1 + oc), bb1 = *(const float4*)(b1 + oc + 4);
        uint4 h0, h1;
        {
            const u16* hs = (const u16*)&a0;
            float v[8];
            v[0] = fmaxf(fmaf(bf2f(hs[0]), sc0.x, bb0.x), 0.f);
            v[1] = fmaxf(fmaf(bf2f(hs[1]), sc0.y, bb0.y), 0.f);
            v[2] = fmaxf(fmaf(bf2f(hs[2]), sc0.z, bb0.z), 0.f);
            v[3] = fmaxf(fmaf(bf2f(hs[3]), sc0.w, bb0.w), 0.f);
            v[4] = fmaxf(fmaf(bf2f(hs[4]), sc1.x, bb1.x), 0.f);
            v[5] = fmaxf(fmaf(bf2f(hs[5]), sc1.y, bb1.y), 0.f);
            v[6] = fmaxf(fmaf(bf2f(hs[6]), sc1.z, bb1.z), 0.f);
            v[7] = fmaxf(fmaf(bf2f(hs[7]), sc1.w, bb1.w), 0.f);
            h0.x = pack2(v[0], v[1]); h0.y = pack2(v[2], v[3]);
            h0.z = pack2(v[4], v[5]); h0.w = pack2(v[6], v[7]);
        }
        {
            const u16* hs = (const u16*)&a1;
            float v[8];
            v[0] = fmaxf(fmaf(bf2f(hs[0]), sc0.x, bb0.x), 0.f);
            v[1] = fmaxf(fmaf(bf2f(hs[1]), sc0.y, bb0.y), 0.f);
            v[2] = fmaxf(fmaf(bf2f(hs[2]), sc0.z, bb0.z), 0.f);
            v[3] = fmaxf(fmaf(bf2f(hs[3]), sc0.w, bb0.w), 0.f);
            v[4] = fmaxf(fmaf(bf2f(hs[4]), sc1.x, bb1.x), 0.f);
            v[5] = fmaxf(fmaf(bf2f(hs[5]), sc1.y, bb1.y), 0.f);
            v[6] = fmaxf(fmaf(bf2f(hs[6]), sc1.z, bb1.z), 0.f);
            v[7] = fmaxf(fmaf(bf2f(hs[7]), sc1.w, bb1.w), 0.f);
            h1.x = pack2(v[0], v[1]); h1.y = pack2(v[2], v[3]);
            h1.z = pack2(v[4], v[5]); h1.w = pack2(v[6], v[7]);
        }
        __syncthreads();
        *(uint4*)aD0 = h0; *(uint4*)aD1 = h1;
        *(uint4*)bD0 = pack8(f00, f01); *(uint4*)bD1 = pack8(f10, f11);
        __syncthreads();
        if (ks < 7) {
            int ko = (ks + 1) * 32;
            a0 = *(const uint4*)(aS0 + ko); a1 = *(const uint4*)(aS1 + ko);
            f00 = *(const float4*)(bS0 + ko); f01 = *(const float4*)(bS0 + ko + 4);
            f10 = *(const float4*)(bS1 + ko); f11 = *(const float4*)(bS1 + ko + 4);
        }
        const u16* ap = &As[(wr * 64 + col) * 40 + q * 8];
        const u16* bp = &Bs[(wc * 64 + col) * 40 + q * 8];
        bf16x8 af[4], bfr[4];
#pragma unroll
        for (int m = 0; m < 4; ++m) af[m] = *(const bf16x8*)(ap + m * 640);
#pragma unroll
        for (int n = 0; n < 4; ++n) bfr[n] = *(const bf16x8*)(bp + n * 640);
#pragma unroll
        for (int m = 0; m < 4; ++m)
#pragma unroll
            for (int n = 0; n < 4; ++n)
                acc[m][n] = __builtin_amdgcn_mfma_f32_16x16x32_bf16(af[m], bfr[n], acc[m][n], 0, 0, 0);
    }
#pragma unroll
    for (int m = 0; m < 4; ++m)
#pragma unroll
        for (int n = 0; n < 4; ++n) {
            int go = wc * 64 + n * 16 + col;
#pragma unroll
            for (int r = 0; r < 4; ++r) {
                int gi = i0 + wr * 64 + m * 16 + q * 4 + r;
                y2[((size_t)(b * N_ + gi)) * O2_ + go] = acc[m][n][r];
            }
        }
}

// ---------------------------- BN2 affine + ReLU + transpose (b,i,o)->(b,o,i) out
__global__ __launch_bounds__(256) void k_out(const float* __restrict__ y2,
                                             const float* __restrict__ s2,
                                             const float* __restrict__ b2,
                                             float* __restrict__ out) {
    __shared__ float lt[64 * 65];
    const int t = threadIdx.x, b = blockIdx.z;
    const int i0 = blockIdx.x * 64, o0 = blockIdx.y * 64;
    const int oc = t & 63, ir4 = t >> 6;
    const float sc = s2[o0 + oc], bs = b2[o0 + oc];
#pragma unroll
    for (int p = 0; p < 16; ++p) {
        int i = i0 + ir4 + p * 4;
        float v = y2[((size_t)(b * N_ + i)) * O2_ + o0 + oc];
        lt[oc * 65 + ir4 + p * 4] = fmaxf(fmaf(v, sc, bs), 0.f);
    }
    __syncthreads();
    const int il = t & 63, or4 = t >> 6;
#pragma unroll
    for (int p = 0; p < 16; ++p) {
        int o = o0 + or4 + p * 4;
        out[((size_t)(b * O2_ + o)) * N_ + i0 + il] = lt[(or4 + p * 4) * 65 + il];
    }
}

extern "C" void kernel_launch(void* const* d_in, const int* in_sizes, int n_in,
                              void* d_out, int out_size, void* d_ws, size_t ws_size,
                              hipStream_t stream) {
    const float* unknown = (const float*)d_in[0];
    const float* known   = (const float*)d_in[1];
    const float* uf      = (const float*)d_in[2];
    const float* kf      = (const float*)d_in[3];
    const float* w1      = (const float*)d_in[4];
    const float* g1      = (const float*)d_in[5];
    const float* be1     = (const float*)d_in[6];
    const float* w2      = (const float*)d_in[7];
    const float* g2      = (const float*)d_in[8];
    const float* be2     = (const float*)d_in[9];
    float* out = (float*)d_out;

    char* w = (char*)d_ws;
    // stats block (zeroed each call): bn1_sum[256] bn1_sq[256] bn2_sum[128] bn2_sq[128]
    float* bn1_sum = (float*)w;
    float* bn1_sq  = bn1_sum + 256;
    float* bn2_sum = bn1_sq + 256;
    float* bn2_sq  = bn2_sum + 128;
    float* s1 = (float*)(w + 4096);     // 256
    float* b1 = s1 + 256;               // 256
    float* s2 = b1 + 256;               // 128
    float* b2 = s2 + 128;               // 128
    int* idx = (int*)(w + 8192);                        // 512 KiB
    u16* newF = (u16*)(w + 532480);                     // (B,n,384) bf16 = 100.7 MB
    float* y2 = (float*)(w + 532480);                   // alias (newF dead by GEMM2)
    size_t R2 = 532480 + 100663296ULL;
    // NN scratch (dead before y1 is written):
    u16*   Aprep = (u16*)(w + R2);                      // 4 MiB (4096 tiles * 1KB)
    u16*   Bprep = (u16*)(w + R2 + 4194304ULL);         // 1 MiB (1024 tiles * 1KB)
    float4* kco  = (float4*)(w + R2 + 5242880ULL);      // 512 KiB
    unsigned long long* pc = (unsigned long long*)(w + R2 + 5767168ULL); // 2 MiB
    u16*  kfT = (u16*)(w + R2 + 16777216ULL);           // 16.7MB (dead before y1)
    u16*   y1 = (u16*)(w + R2);                         // (B,n,256) bf16 = 67 MB

    hipMemsetAsync(w, 0, 3072, stream);   // zero BN accumulators

    k_prep_u<<<512, 256, 0, stream>>>(unknown, Aprep);
    k_prep_k<<<128, 256, 0, stream>>>(known, Bprep, kco);
    k_nn<<<dim3(N_ / 128, 2, B_), 256, 0, stream>>>(Aprep, Bprep, unknown, kco, pc);
    k_nn_merge<<<512, 256, 0, stream>>>(pc, idx);
    k_tr_kf<<<dim3(256, 4, 2), 256, 0, stream>>>(kf, kfT);
    k_tr_uf<<<dim3(1024, 2, 2), 256, 0, stream>>>(uf, newF);
    k_gather<<<dim3(8192, 2), 256, 0, stream>>>(kfT, idx, newF);
    k_gemm1<<<dim3(512, 2, 2), 256, 0, stream>>>(newF, w1, y1);
    k_stats_bf16<<<128, 256, 0, stream>>>(y1, bn1_sum, bn1_sq);
    k_bn_fin<<<1, 256, 0, stream>>>(bn1_sum, bn1_sq, g1, be1, s1, b1, 256, 1.f / 131072.f);
    k_gemm2<<<dim3(512, 1, 2), 256, 0, stream>>>(y1, w2, s1, b1, y2);
    k_stats_f32<<<128, 256, 0, stream>>>(y2, bn2_sum, bn2_sq);
    k_bn_fin<<<1, 256, 0, stream>>>(bn2_sum, bn2_sq, g2, be2, s2, b2, 128, 1.f / 131072.f);
    k_out<<<dim3(1024, 2, 2), 256, 0, stream>>>(y2, s2, b2, out);
}

// Round 5
// 582.165 us; speedup vs baseline: 1.5516x; 1.0202x over previous
//
#include <hip/hip_runtime.h>

typedef unsigned short u16;
typedef unsigned int u32;
typedef __bf16 bf16x8 __attribute__((ext_vector_type(8)));
typedef _Float16 f16;
typedef _Float16 f16x8 __attribute__((ext_vector_type(8)));
typedef float f32x4 __attribute__((ext_vector_type(4)));
typedef float f32x16 __attribute__((ext_vector_type(16)));

#define B_ 2
#define N_ 65536
#define M_ 16384
#define C1_ 128
#define C2_ 256
#define K1_ 384   // C1+C2
#define O1_ 256   // mlp[1]
#define O2_ 128   // mlp[2]
#define JT_ 512       // 32-wide j-tiles per batch (M_/32)
#define HT_ (JT_/2)   // j-tiles per half = 256
#define EPS2_ 6.0e-3f // 2*eps certified ordering slack (verified rounds 1-4)
#define TFIN_ 1.25e-4f // threshold-fold inflation; >= 4x worst-case fold error
                       // => thr' > thr strictly => sign-test (<0) catches all
                       // certified-needed candidates

__device__ __forceinline__ u16 f2bf(float f) {
    u32 u = __float_as_uint(f);
    u32 r = (u + 0x7FFFu + ((u >> 16) & 1u)) >> 16;   // RNE
    return (u16)r;
}
__device__ __forceinline__ float bf2f(u16 h) {
    return __uint_as_float(((u32)h) << 16);
}
__device__ __forceinline__ u32 pack2(float lo, float hi) {
    return (u32)f2bf(lo) | ((u32)f2bf(hi) << 16);
}
__device__ __forceinline__ uint4 pack8(float4 a, float4 b) {
    uint4 r;
    r.x = pack2(a.x, a.y); r.y = pack2(a.z, a.w);
    r.z = pack2(b.x, b.y); r.w = pack2(b.z, b.w);
    return r;
}
__device__ __forceinline__ u16 h2u(f16 h) {
    union { f16 h; u16 u; } c; c.h = h; return c.u;
}

// Exact-IEEE fp32 mul with an optimization barrier so the backend can NEVER
// contract it into an FMA (HIP default is -ffp-contract=fast).
__device__ __forceinline__ float mul_rn(float a, float b) {
    float p = __fmul_rn(a, b);
    asm volatile("" : "+v"(p));
    return p;
}
// u2/k2: elementwise-square (each product rounded) + ascending reduce
__device__ __forceinline__ float sq3_np(float x, float y, float z) {
    return __fadd_rn(__fadd_rn(mul_rn(x, x), mul_rn(y, y)), mul_rn(z, z));
}
// Eigen/XLA gebp K=3 dot: ascending k, FMA accumulate into rounded first product
__device__ __forceinline__ float dot3_fma(float a0, float b0, float a1, float b1,
                                          float a2, float b2) {
    return fmaf(a2, b2, fmaf(a1, b1, mul_rn(a0, b0)));
}

// ============================== NN search: 32x32x16 MFMA filter + exact refine
// Numerics identical to the round-3/4 kernels (passed, bit-exact indices):
// key val_ij = k2_j - 2*dot_ij via mfma_f32_32x32x16_f16; K-slots 0-8 split
// coords (A has -2 folded), 9-10 k2 hi/lo (A=1.0), 11-12 pass-B threshold fold
// (A=-(thr+TFIN_) hi/lo, B=1.0) => MFMA emits val - thr' with thr' > thr
// strictly => every certified-needed candidate has a strictly NEGATIVE key
// => sign-bit OR test suffices; exact refine reproduces reference argmin.
// Restructure vs r4 (anti-barrier): NO LDS staging, NO barriers at all.
// B-fragments stream per-lane from L2 (Bprep halves are 256 KB, L2-resident),
// 2-tile-ahead register rotation; each wave owns TWO 32-row tiles (64 rows) so
// one B-fragment feeds 2 MFMAs (halves L2 traffic, ~2.1 GB total). thrS/cand
// LDS slices are wave-private (rows are wave-local) -> lgkmcnt ordering only.

__global__ __launch_bounds__(256) void k_prep_u(const float* __restrict__ unk,
                                                u16* __restrict__ Aprep) {
    int g = blockIdx.x * 256 + threadIdx.x;          // over B*N
    const float* up = unk + (size_t)g * 3;
    float tx = -2.f * up[0], ty = -2.f * up[1], tz = -2.f * up[2];
    f16 xh = (f16)tx; f16 xl = (f16)(tx - (float)xh);
    f16 yh = (f16)ty; f16 yl = (f16)(ty - (float)yh);
    f16 zh = (f16)tz; f16 zl = (f16)(tz - (float)zh);
    u16 lo[8] = {h2u(xh), h2u(xh), h2u(xl), h2u(yh), h2u(yh), h2u(yl), h2u(zh), h2u(zh)};
    u16 hi[8] = {h2u(zl), 0x3C00u, 0x3C00u, 0, 0, 0, 0, 0};
    u16* tb = Aprep + ((size_t)(g >> 5)) * 512;      // tile = 64 lanes * 8 u16
    int r = g & 31;
    *(uint4*)(tb + r * 8) = *(uint4*)lo;
    *(uint4*)(tb + (r + 32) * 8) = *(uint4*)hi;
}

__global__ __launch_bounds__(256) void k_prep_k(const float* __restrict__ kn,
                                                u16* __restrict__ Bprep,
                                                float4* __restrict__ kco) {
    int g = blockIdx.x * 256 + threadIdx.x;          // over B*M
    const float* kp = kn + (size_t)g * 3;
    float x = kp[0], y = kp[1], z = kp[2];
    float qv = sq3_np(x, y, z);                       // EXACT ref k2 sequence
    f16 xh = (f16)x; f16 xl = (f16)(x - (float)xh);
    f16 yh = (f16)y; f16 yl = (f16)(y - (float)yh);
    f16 zh = (f16)z; f16 zl = (f16)(z - (float)zh);
    f16 qh = (f16)qv; f16 ql = (f16)(qv - (float)qh);
    u16 lo[8] = {h2u(xh), h2u(xl), h2u(xh), h2u(yh), h2u(yl), h2u(yh), h2u(zh), h2u(zl)};
    // slots 11,12 = 1.0 so pass B's A-side -thr hi/lo ride the same MFMA
    u16 hi[8] = {h2u(zh), h2u(qh), h2u(ql), 0x3C00u, 0x3C00u, 0, 0, 0};
    u16* tb = Bprep + ((size_t)(g >> 5)) * 512;
    int r = g & 31;
    *(uint4*)(tb + r * 8) = *(uint4*)lo;
    *(uint4*)(tb + (r + 32) * 8) = *(uint4*)hi;
    kco[g] = make_float4(x, y, z, qv);
}

__global__ __launch_bounds__(256, 4) void k_nn(
        const u16* __restrict__ Aprep, const u16* __restrict__ Bprep,
        const float* __restrict__ unk, const float4* __restrict__ kco,
        unsigned long long* __restrict__ pc) {
    __shared__ unsigned long long cand[256];   // wave-private 64-row slices
    __shared__ float thrS[256];                // wave-private 64-row slices
    const int t = threadIdx.x;
    const int half = blockIdx.y, b = blockIdx.z;
    const int lane = t & 63, w = t >> 6;
    const int rowbase = blockIdx.x * 256;            // 256 rows per block
    // wave w owns rows [rowbase + w*64, +64) = two 32-row tiles
    const u16* at = Aprep + (((size_t)(b * N_ + rowbase + w * 64)) >> 5) * 512;
    f16x8 af0 = *(const f16x8*)(at + lane * 8);
    f16x8 af1 = *(const f16x8*)(at + 512 + lane * 8);
    const u16* Bp = Bprep + ((size_t)b * JT_ + (size_t)half * HT_) * 512 + lane * 8;
    cand[t] = ~0ULL;

    const f32x16 zz = {0.f,0.f,0.f,0.f,0.f,0.f,0.f,0.f,0.f,0.f,0.f,0.f,0.f,0.f,0.f,0.f};

    // ---------------- pass A: rowmin over this j-half (no barriers) ---------
    f32x16 rm0, rm1;
#pragma unroll
    for (int r = 0; r < 16; ++r) { rm0[r] = 3.4e38f; rm1[r] = 3.4e38f; }

    // 2-tile-ahead rotation; final prefetch reads <=2 KB past this half
    // (next half / kco region -- mapped workspace, values unused).
    f16x8 c0 = *(const f16x8*)Bp;
    f16x8 c1 = *(const f16x8*)(Bp + 512);
    for (int tp = 0; tp < HT_; tp += 2) {
        f16x8 n0 = *(const f16x8*)(Bp + 1024);
        f16x8 n1 = *(const f16x8*)(Bp + 1536);
        Bp += 1024;
        f32x16 a  = __builtin_amdgcn_mfma_f32_32x32x16_f16(af0, c0, zz, 0, 0, 0);
        f32x16 ca = __builtin_amdgcn_mfma_f32_32x32x16_f16(af0, c1, zz, 0, 0, 0);
#pragma unroll
        for (int r = 0; r < 16; ++r)
            rm0[r] = fminf(fminf(rm0[r], a[r]), ca[r]);
        a  = __builtin_amdgcn_mfma_f32_32x32x16_f16(af1, c0, zz, 0, 0, 0);
        ca = __builtin_amdgcn_mfma_f32_32x32x16_f16(af1, c1, zz, 0, 0, 0);
#pragma unroll
        for (int r = 0; r < 16; ++r)
            rm1[r] = fminf(fminf(rm1[r], a[r]), ca[r]);
        c0 = n0; c1 = n1;
    }

    // reduce over the 32 cols -> per-row thresholds (wave-private LDS slice)
#pragma unroll
    for (int r = 0; r < 16; ++r) {
        float v0 = rm0[r], v1 = rm1[r];
        v0 = fminf(v0, __shfl_xor(v0, 1));  v1 = fminf(v1, __shfl_xor(v1, 1));
        v0 = fminf(v0, __shfl_xor(v0, 2));  v1 = fminf(v1, __shfl_xor(v1, 2));
        v0 = fminf(v0, __shfl_xor(v0, 4));  v1 = fminf(v1, __shfl_xor(v1, 4));
        v0 = fminf(v0, __shfl_xor(v0, 8));  v1 = fminf(v1, __shfl_xor(v1, 8));
        v0 = fminf(v0, __shfl_xor(v0, 16)); v1 = fminf(v1, __shfl_xor(v1, 16));
        if ((lane & 31) == 0) {
            int rl = w * 64 + ((lane >> 5) << 2) + (r & 3) + 8 * (r >> 2);
            thrS[rl] = v0 + EPS2_;
            thrS[rl + 32] = v1 + EPS2_;
        }
    }
    // patch A fragments: k-slots 11,12 (lanes>=32, elems 3,4) = -(thr+TFIN_)
    // (same-wave LDS RAW -> compiler-inserted lgkmcnt wait; no barrier needed)
    if (lane >= 32) {
        float tf0 = thrS[w * 64 + (lane & 31)] + TFIN_;
        f16 h0 = (f16)(-tf0);
        af0[3] = h0; af0[4] = (f16)(-tf0 - (float)h0);
        float tf1 = thrS[w * 64 + 32 + (lane & 31)] + TFIN_;
        f16 h1 = (f16)(-tf1);
        af1[3] = h1; af1[4] = (f16)(-tf1 - (float)h1);
    }

    // ---------------- pass B: exact refine (MFMA emits val - thr') ----------
    const float4* kcb = kco + (size_t)b * M_;
    const float* ub = unk + (size_t)b * N_ * 3;
    const int rloc0 = w * 64 + ((lane >> 5) << 2);   // + (r&3)+8*(r>>2) [+32 rt1]
    const int jb0 = half * (M_ / 2);

    Bp -= (size_t)HT_ * 512;                         // rewind to half start
    c0 = *(const f16x8*)Bp;
    f16x8 c1b = *(const f16x8*)(Bp + 512);
    for (int tt = 0; tt < HT_; ++tt) {
        f16x8 nx = *(const f16x8*)(Bp + 1024);
        Bp += 512;
        f32x16 a0 = __builtin_amdgcn_mfma_f32_32x32x16_f16(af0, c0, zz, 0, 0, 0);
        f32x16 a1 = __builtin_amdgcn_mfma_f32_32x32x16_f16(af1, c0, zz, 0, 0, 0);
        // candidate iff key < 0 (threshold folded): OR the sign bits
        u32 o = 0;
#pragma unroll
        for (int r = 0; r < 16; ++r)
            o |= __float_as_uint(a0[r]) | __float_as_uint(a1[r]);
        if (__ballot((int)o < 0)) {                  // rarely taken
            int j = jb0 + tt * 32 + (lane & 31);
            float4 kc = kcb[j];
#pragma unroll
            for (int r = 0; r < 16; ++r) {
                if (a0[r] <= 0.f) {
                    int rl = rloc0 + (r & 3) + 8 * (r >> 2);
                    const float* up = ub + (size_t)(rowbase + rl) * 3;
                    float x = up[0], y = up[1], zc = up[2];
                    float uq = sq3_np(x, y, zc);
                    float dot = dot3_fma(x, kc.x, y, kc.y, zc, kc.z);
                    float d = __fadd_rn(fmaf(-2.0f, dot, uq), kc.w);
                    u32 db = __float_as_uint(d);
                    db = (db & 0x80000000u) ? ~db : (db | 0x80000000u);
                    atomicMin(&cand[rl], ((unsigned long long)db << 32) | (u32)j);
                }
                if (a1[r] <= 0.f) {
                    int rl = rloc0 + 32 + (r & 3) + 8 * (r >> 2);
                    const float* up = ub + (size_t)(rowbase + rl) * 3;
                    float x = up[0], y = up[1], zc = up[2];
                    float uq = sq3_np(x, y, zc);
                    float dot = dot3_fma(x, kc.x, y, kc.y, zc, kc.z);
                    float d = __fadd_rn(fmaf(-2.0f, dot, uq), kc.w);
                    u32 db = __float_as_uint(d);
                    db = (db & 0x80000000u) ? ~db : (db | 0x80000000u);
                    atomicMin(&cand[rl], ((unsigned long long)db << 32) | (u32)j);
                }
            }
        }
        c0 = c1b; c1b = nx;
    }
    // cand[t] belongs to wave t>>6 (rows are wave-local) -> no barrier
    pc[((size_t)(half * B_ + b)) * N_ + rowbase + t] = cand[t];
}

// merge the two j-half packed mins; lower half has smaller j => tie-break ok
__global__ __launch_bounds__(256) void k_nn_merge(
        const unsigned long long* __restrict__ pc, int* __restrict__ idx) {
    int g = blockIdx.x * 256 + threadIdx.x;          // over B*N
    unsigned long long a = pc[g];
    unsigned long long c = pc[(size_t)(B_ * N_) + g];
    idx[g] = (int)(u32)((c < a ? c : a) & 0xFFFFFFFFu);
}

// ------------------------------------------- transpose known_feats -> (b,m,c) bf16
__global__ __launch_bounds__(256) void k_tr_kf(const float* __restrict__ kf,
                                               u16* __restrict__ kfT) {
    __shared__ float lt[64][65];
    const int t = threadIdx.x, b = blockIdx.z;
    const int j0 = blockIdx.x * 64, c0 = blockIdx.y * 64;
    const int jl = t & 63, cl4 = t >> 6;
#pragma unroll
    for (int p = 0; p < 16; ++p) {
        int c = c0 + cl4 + p * 4;
        lt[cl4 + p * 4][jl] = kf[((size_t)(b * C2_ + c)) * M_ + j0 + jl];
    }
    __syncthreads();
    const int cl = t & 63, jr4 = t >> 6;
#pragma unroll
    for (int p = 0; p < 16; ++p) {
        int j = j0 + jr4 + p * 4;
        kfT[((size_t)(b * M_ + j)) * C2_ + c0 + cl] = f2bf(lt[cl][jr4 + p * 4]);
    }
}

// ------------------------------- transpose unknow_feats into newF[...,256:384) bf16
__global__ __launch_bounds__(256) void k_tr_uf(const float* __restrict__ uf,
                                               u16* __restrict__ newF) {
    __shared__ float lt[64][65];
    const int t = threadIdx.x, b = blockIdx.z;
    const int i0 = blockIdx.x * 64, c0 = blockIdx.y * 64;
    const int il = t & 63, cl4 = t >> 6;
#pragma unroll
    for (int p = 0; p < 16; ++p) {
        int c = c0 + cl4 + p * 4;
        lt[cl4 + p * 4][il] = uf[((size_t)(b * C1_ + c)) * N_ + i0 + il];
    }
    __syncthreads();
    const int cl = t & 63, ir4 = t >> 6;
#pragma unroll
    for (int p = 0; p < 16; ++p) {
        int i = i0 + ir4 + p * 4;
        newF[((size_t)(b * N_ + i)) * K1_ + C2_ + c0 + cl] = f2bf(lt[cl][ir4 + p * 4]);
    }
}

// ------------------------------------ gather kfT rows into newF[...,0:256) (dense)
__global__ __launch_bounds__(256) void k_gather(const u16* __restrict__ kfT,
                                                const int* __restrict__ idx,
                                                u16* __restrict__ newF) {
    const int t = threadIdx.x, b = blockIdx.y;
    const int il = t >> 5, qq = t & 31;
    const int i = blockIdx.x * 8 + il;
    const int j = idx[b * N_ + i];
    const uint4* src = (const uint4*)(kfT + ((size_t)(b * M_ + j)) * C2_) + qq;
    uint4* dst = (uint4*)(newF + ((size_t)(b * N_ + i)) * K1_) + qq;
    *dst = *src;
}

// ---------------------------------------------------------------- GEMM1
// y1[b][i][o] (bf16) = newF[b][i][:] . w1[o][:]   tiles 128x128, BK=32
__global__ __launch_bounds__(256) void k_gemm1(const u16* __restrict__ newF,
                                               const float* __restrict__ w1,
                                               u16* __restrict__ y1) {
    __shared__ u16 As[128 * 40];
    __shared__ u16 Bs[128 * 40];
    const int t = threadIdx.x, b = blockIdx.z;
    const int i0 = blockIdx.x * 128, o0 = blockIdx.y * 128;
    const int lane = t & 63, wv = t >> 6, wr = wv >> 1, wc = wv & 1;
    const int col = lane & 15, q = lane >> 4;

    const int rA0 = t >> 2, sA0 = t & 3;   // +256 => row+64, same sub
    const u16* aS0 = newF + ((size_t)(b * N_ + i0 + rA0)) * K1_ + sA0 * 8;
    const u16* aS1 = aS0 + (size_t)64 * K1_;
    const float* bS0 = w1 + (size_t)(o0 + rA0) * K1_ + sA0 * 8;
    const float* bS1 = bS0 + (size_t)64 * K1_;
    u16* aD0 = &As[rA0 * 40 + sA0 * 8];
    u16* aD1 = aD0 + 64 * 40;
    u16* bD0 = &Bs[rA0 * 40 + sA0 * 8];
    u16* bD1 = bD0 + 64 * 40;

    f32x4 acc[4][4];
#pragma unroll
    for (int m = 0; m < 4; ++m)
#pragma unroll
        for (int n = 0; n < 4; ++n) acc[m][n] = (f32x4){0.f, 0.f, 0.f, 0.f};

    uint4 a0 = *(const uint4*)aS0, a1 = *(const uint4*)aS1;
    float4 f00 = *(const float4*)bS0, f01 = *(const float4*)(bS0 + 4);
    float4 f10 = *(const float4*)bS1, f11 = *(const float4*)(bS1 + 4);

    for (int ks = 0; ks < 12; ++ks) {
        __syncthreads();
        *(uint4*)aD0 = a0; *(uint4*)aD1 = a1;
        *(uint4*)bD0 = pack8(f00, f01); *(uint4*)bD1 = pack8(f10, f11);
        __syncthreads();
        if (ks < 11) {
            int ko = (ks + 1) * 32;
            a0 = *(const uint4*)(aS0 + ko); a1 = *(const uint4*)(aS1 + ko);
            f00 = *(const float4*)(bS0 + ko); f01 = *(const float4*)(bS0 + ko + 4);
            f10 = *(const float4*)(bS1 + ko); f11 = *(const float4*)(bS1 + ko + 4);
        }
        const u16* ap = &As[(wr * 64 + col) * 40 + q * 8];
        const u16* bp = &Bs[(wc * 64 + col) * 40 + q * 8];
        bf16x8 af[4], bfr[4];
#pragma unroll
        for (int m = 0; m < 4; ++m) af[m] = *(const bf16x8*)(ap + m * 640);
#pragma unroll
        for (int n = 0; n < 4; ++n) bfr[n] = *(const bf16x8*)(bp + n * 640);
#pragma unroll
        for (int m = 0; m < 4; ++m)
#pragma unroll
            for (int n = 0; n < 4; ++n)
                acc[m][n] = __builtin_amdgcn_mfma_f32_16x16x32_bf16(af[m], bfr[n], acc[m][n], 0, 0, 0);
    }
#pragma unroll
    for (int m = 0; m < 4; ++m)
#pragma unroll
        for (int n = 0; n < 4; ++n) {
            int go = o0 + wc * 64 + n * 16 + col;
#pragma unroll
            for (int r = 0; r < 4; ++r) {
                int gi = i0 + wr * 64 + m * 16 + q * 4 + r;
                y1[((size_t)(b * N_ + gi)) * O1_ + go] = f2bf(acc[m][n][r]);
            }
        }
}

// ------------------------------------------------- BN stats over y1 (bf16, 256 ch)
__global__ __launch_bounds__(256) void k_stats_bf16(const u16* __restrict__ y1,
                                                    float* __restrict__ sum,
                                                    float* __restrict__ sq) {
    const int t = threadIdx.x;
    const int row0 = blockIdx.x * 1024;
    float s = 0.f, qq = 0.f;
    for (int r = 0; r < 1024; ++r) {
        float v = bf2f(y1[((size_t)(row0 + r)) * O1_ + t]);
        s += v; qq = fmaf(v, v, qq);
    }
    atomicAdd(&sum[t], s);
    atomicAdd(&sq[t], qq);
}

// ------------------------------------------------- BN stats over y2 (f32, 128 ch)
__global__ __launch_bounds__(256) void k_stats_f32(const float* __restrict__ y2,
                                                   float* __restrict__ sum,
                                                   float* __restrict__ sq) {
    const int t = threadIdx.x;
    const int o = t & 127, h = t >> 7;
    const int row0 = blockIdx.x * 1024;
    float s = 0.f, qq = 0.f;
    for (int r = 0; r < 512; ++r) {
        float v = y2[((size_t)(row0 + r * 2 + h)) * O2_ + o];
        s += v; qq = fmaf(v, v, qq);
    }
    atomicAdd(&sum[o], s);
    atomicAdd(&sq[o], qq);
}

__global__ void k_bn_fin(const float* __restrict__ sum, const float* __restrict__ sq,
                         const float* __restrict__ gamma, const float* __restrict__ beta,
                         float* __restrict__ scale, float* __restrict__ bias,
                         int C, float invN) {
    int t = threadIdx.x;
    if (t < C) {
        float mean = sum[t] * invN;
        float var = sq[t] * invN - mean * mean;
        float rs = rsqrtf(var + 1e-5f);
        float sc = gamma[t] * rs;
        scale[t] = sc;
        bias[t] = beta[t] - mean * sc;
    }
}

// ---------------------------------------------------------------- GEMM2
// y2[b][i][o] (f32) = relu(bn1(y1))[b][i][:] . w2[o][:]  (BN1 fused in A-staging)
__global__ __launch_bounds__(256) void k_gemm2(const u16* __restrict__ y1,
                                               const float* __restrict__ w2,
                                               const float* __restrict__ s1,
                                               const float* __restrict__ b1,
                                               float* __restrict__ y2) {
    __shared__ u16 As[128 * 40];
    __shared__ u16 Bs[128 * 40];
    const int t = threadIdx.x, b = blockIdx.z;
    const int i0 = blockIdx.x * 128;
    const int lane = t & 63, wv = t >> 6, wr = wv >> 1, wc = wv & 1;
    const int col = lane & 15, q = lane >> 4;

    const int rA0 = t >> 2, sA0 = t & 3;
    const u16* aS0 = y1 + ((size_t)(b * N_ + i0 + rA0)) * O1_ + sA0 * 8;
    const u16* aS1 = aS0 + (size_t)64 * O1_;
    const float* bS0 = w2 + (size_t)rA0 * O1_ + sA0 * 8;
    const float* bS1 = bS0 + (size_t)64 * O1_;
    u16* aD0 = &As[rA0 * 40 + sA0 * 8];
    u16* aD1 = aD0 + 64 * 40;
    u16* bD0 = &Bs[rA0 * 40 + sA0 * 8];
    u16* bD1 = bD0 + 64 * 40;

    f32x4 acc[4][4];
#pragma unroll
    for (int m = 0; m < 4; ++m)
#pragma unroll
        for (int n = 0; n < 4; ++n) acc[m][n] = (f32x4){0.f, 0.f, 0.f, 0.f};

    uint4 a0 = *(const uint4*)aS0, a1 = *(const uint4*)aS1;
    float4 f00 = *(const float4*)bS0, f01 = *(const float4*)(bS0 + 4);
    float4 f10 = *(const float4*)bS1, f11 = *(const float4*)(bS1 + 4);

    for (int ks = 0; ks < 8; ++ks) {
        int oc = ks * 32 + sA0 * 8;
        float4 sc0 = *(const float4*)(s1 + oc), sc1 = *(const float4*)(s1 + oc + 4);
        float4 bb0 = *(const float4*)(b1 + oc), bb1 = *(const float4*)(b1 + oc + 4);
        uint4 h0, h1;
        {
            const u16* hs = (const u16*)&a0;
            float v[8];
            v[0] = fmaxf(fmaf(bf2f(hs[0]), sc0.x, bb0.x), 0.f);
            v[1] = fmaxf(fmaf(bf2f(hs[1]), sc0.y, bb0.y), 0.f);
            v[2] = fmaxf(fmaf(bf2f(hs[2]), sc0.z, bb0.z), 0.f);
            v[3] = fmaxf(fmaf(bf2f(hs[3]), sc0.w, bb0.w), 0.f);
            v[4] = fmaxf(fmaf(bf2f(hs[4]), sc1.x, bb1.x), 0.f);
            v[5] = fmaxf(fmaf(bf2f(hs[5]), sc1.y, bb1.y), 0.f);
            v[6] = fmaxf(fmaf(bf2f(hs[6]), sc1.z, bb1.z), 0.f);
            v[7] = fmaxf(fmaf(bf2f(hs[7]), sc1.w, bb1.w), 0.f);
            h0.x = pack2(v[0], v[1]); h0.y = pack2(v[2], v[3]);
            h0.z = pack2(v[4], v[5]); h0.w = pack2(v[6], v[7]);
        }
        {
            const u16* hs = (const u16*)&a1;
            float v[8];
            v[0] = fmaxf(fmaf(bf2f(hs[0]), sc0.x, bb0.x), 0.f);
            v[1] = fmaxf(fmaf(bf2f(hs[1]), sc0.y, bb0.y), 0.f);
            v[2] = fmaxf(fmaf(bf2f(hs[2]), sc0.z, bb0.z), 0.f);
            v[3] = fmaxf(fmaf(bf2f(hs[3]), sc0.w, bb0.w), 0.f);
            v[4] = fmaxf(fmaf(bf2f(hs[4]), sc1.x, bb1.x), 0.f);
            v[5] = fmaxf(fmaf(bf2f(hs[5]), sc1.y, bb1.y), 0.f);
            v[6] = fmaxf(fmaf(bf2f(hs[6]), sc1.z, bb1.z), 0.f);
            v[7] = fmaxf(fmaf(bf2f(hs[7]), sc1.w, bb1.w), 0.f);
            h1.x = pack2(v[0], v[1]); h1.y = pack2(v[2], v[3]);
            h1.z = pack2(v[4], v[5]); h1.w = pack2(v[6], v[7]);
        }
        __syncthreads();
        *(uint4*)aD0 = h0; *(uint4*)aD1 = h1;
        *(uint4*)bD0 = pack8(f00, f01); *(uint4*)bD1 = pack8(f10, f11);
        __syncthreads();
        if (ks < 7) {
            int ko = (ks + 1) * 32;
            a0 = *(const uint4*)(aS0 + ko); a1 = *(const uint4*)(aS1 + ko);
            f00 = *(const float4*)(bS0 + ko); f01 = *(const float4*)(bS0 + ko + 4);
            f10 = *(const float4*)(bS1 + ko); f11 = *(const float4*)(bS1 + ko + 4);
        }
        const u16* ap = &As[(wr * 64 + col) * 40 + q * 8];
        const u16* bp = &Bs[(wc * 64 + col) * 40 + q * 8];
        bf16x8 af[4], bfr[4];
#pragma unroll
        for (int m = 0; m < 4; ++m) af[m] = *(const bf16x8*)(ap + m * 640);
#pragma unroll
        for (int n = 0; n < 4; ++n) bfr[n] = *(const bf16x8*)(bp + n * 640);
#pragma unroll
        for (int m = 0; m < 4; ++m)
#pragma unroll
            for (int n = 0; n < 4; ++n)
                acc[m][n] = __builtin_amdgcn_mfma_f32_16x16x32_bf16(af[m], bfr[n], acc[m][n], 0, 0, 0);
    }
#pragma unroll
    for (int m = 0; m < 4; ++m)
#pragma unroll
        for (int n = 0; n < 4; ++n) {
            int go = wc * 64 + n * 16 + col;
#pragma unroll
            for (int r = 0; r < 4; ++r) {
                int gi = i0 + wr * 64 + m * 16 + q * 4 + r;
                y2[((size_t)(b * N_ + gi)) * O2_ + go] = acc[m][n][r];
            }
        }
}

// ---------------------------- BN2 affine + ReLU + transpose (b,i,o)->(b,o,i) out
__global__ __launch_bounds__(256) void k_out(const float* __restrict__ y2,
                                             const float* __restrict__ s2,
                                             const float* __restrict__ b2,
                                             float* __restrict__ out) {
    __shared__ float lt[64 * 65];
    const int t = threadIdx.x, b = blockIdx.z;
    const int i0 = blockIdx.x * 64, o0 = blockIdx.y * 64;
    const int oc = t & 63, ir4 = t >> 6;
    const float sc = s2[o0 + oc], bs = b2[o0 + oc];
#pragma unroll
    for (int p = 0; p < 16; ++p) {
        int i = i0 + ir4 + p * 4;
        float v = y2[((size_t)(b * N_ + i)) * O2_ + o0 + oc];
        lt[oc * 65 + ir4 + p * 4] = fmaxf(fmaf(v, sc, bs), 0.f);
    }
    __syncthreads();
    const int il = t & 63, or4 = t >> 6;
#pragma unroll
    for (int p = 0; p < 16; ++p) {
        int o = o0 + or4 + p * 4;
        out[((size_t)(b * O2_ + o)) * N_ + i0 + il] = lt[(or4 + p * 4) * 65 + il];
    }
}

extern "C" void kernel_launch(void* const* d_in, const int* in_sizes, int n_in,
                              void* d_out, int out_size, void* d_ws, size_t ws_size,
                              hipStream_t stream) {
    const float* unknown = (const float*)d_in[0];
    const float* known   = (const float*)d_in[1];
    const float* uf      = (const float*)d_in[2];
    const float* kf      = (const float*)d_in[3];
    const float* w1      = (const float*)d_in[4];
    const float* g1      = (const float*)d_in[5];
    const float* be1     = (const float*)d_in[6];
    const float* w2      = (const float*)d_in[7];
    const float* g2      = (const float*)d_in[8];
    const float* be2     = (const float*)d_in[9];
    float* out = (float*)d_out;

    char* w = (char*)d_ws;
    // stats block (zeroed each call): bn1_sum[256] bn1_sq[256] bn2_sum[128] bn2_sq[128]
    float* bn1_sum = (float*)w;
    float* bn1_sq  = bn1_sum + 256;
    float* bn2_sum = bn1_sq + 256;
    float* bn2_sq  = bn2_sum + 128;
    float* s1 = (float*)(w + 4096);     // 256
    float* b1 = s1 + 256;               // 256
    float* s2 = b1 + 256;               // 128
    float* b2 = s2 + 128;               // 128
    int* idx = (int*)(w + 8192);                        // 512 KiB
    u16* newF = (u16*)(w + 532480);                     // (B,n,384) bf16 = 100.7 MB
    float* y2 = (float*)(w + 532480);                   // alias (newF dead by GEMM2)
    size_t R2 = 532480 + 100663296ULL;
    // NN scratch (dead before y1 is written):
    u16*   Aprep = (u16*)(w + R2);                      // 4 MiB (4096 tiles * 1KB)
    u16*   Bprep = (u16*)(w + R2 + 4194304ULL);         // 1 MiB (1024 tiles * 1KB)
    float4* kco  = (float4*)(w + R2 + 5242880ULL);      // 512 KiB
    unsigned long long* pc = (unsigned long long*)(w + R2 + 5767168ULL); // 2 MiB
    u16*  kfT = (u16*)(w + R2 + 16777216ULL);           // 16.7MB (dead before y1)
    u16*   y1 = (u16*)(w + R2);                         // (B,n,256) bf16 = 67 MB

    hipMemsetAsync(w, 0, 3072, stream);   // zero BN accumulators

    k_prep_u<<<512, 256, 0, stream>>>(unknown, Aprep);
    k_prep_k<<<128, 256, 0, stream>>>(known, Bprep, kco);
    k_nn<<<dim3(N_ / 256, 2, B_), 256, 0, stream>>>(Aprep, Bprep, unknown, kco, pc);
    k_nn_merge<<<512, 256, 0, stream>>>(pc, idx);
    k_tr_kf<<<dim3(256, 4, 2), 256, 0, stream>>>(kf, kfT);
    k_tr_uf<<<dim3(1024, 2, 2), 256, 0, stream>>>(uf, newF);
    k_gather<<<dim3(8192, 2), 256, 0, stream>>>(kfT, idx, newF);
    k_gemm1<<<dim3(512, 2, 2), 256, 0, stream>>>(newF, w1, y1);
    k_stats_bf16<<<128, 256, 0, stream>>>(y1, bn1_sum, bn1_sq);
    k_bn_fin<<<1, 256, 0, stream>>>(bn1_sum, bn1_sq, g1, be1, s1, b1, 256, 1.f / 131072.f);
    k_gemm2<<<dim3(512, 1, 2), 256, 0, stream>>>(y1, w2, s1, b1, y2);
    k_stats_f32<<<128, 256, 0, stream>>>(y2, bn2_sum, bn2_sq);
    k_bn_fin<<<1, 256, 0, stream>>>(bn2_sum, bn2_sq, g2, be2, s2, b2, 128, 1.f / 131072.f);
    k_out<<<dim3(1024, 2, 2), 256, 0, stream>>>(y2, s2, b2, out);
}